// Round 1
// baseline (706.655 us; speedup 1.0000x reference)
//
#include <hip/hip_runtime.h>
#include <cstdint>

#define BLK 256

// ---------------- degree / norm precompute ----------------

__global__ __launch_bounds__(BLK) void k_deg_init(float* __restrict__ deg, int n) {
  int i = blockIdx.x * BLK + threadIdx.x;
  if (i < n) deg[i] = 1.0f;  // self-loop weight
}

__global__ __launch_bounds__(BLK) void k_deg_edge(const float* __restrict__ ew,
                                                  const int* __restrict__ dst,
                                                  float* __restrict__ deg, int E) {
  int e = blockIdx.x * BLK + threadIdx.x;
  if (e < E) unsafeAtomicAdd(&deg[dst[e]], ew[e]);
}

__global__ __launch_bounds__(BLK) void k_dinv(const float* __restrict__ deg,
                                              float* __restrict__ dinv, int n) {
  int i = blockIdx.x * BLK + threadIdx.x;
  if (i < n) {
    float d = deg[i];
    dinv[i] = d > 0.0f ? rsqrtf(d) : 0.0f;
  }
}

__global__ __launch_bounds__(BLK) void k_norm(const int* __restrict__ src,
                                              const int* __restrict__ dst,
                                              const float* __restrict__ ew,
                                              const float* __restrict__ dinv,
                                              float* __restrict__ norm, int E) {
  int e = blockIdx.x * BLK + threadIdx.x;
  if (e < E) norm[e] = dinv[src[e]] * ew[e] * dinv[dst[e]];
}

// ---------------- GEMM1: h1[n,64] = x[n,128] @ W1[128,64] ----------------
// 16 rows/block; W1 (32 KB) + x rows (8 KB) staged in LDS.
__global__ __launch_bounds__(BLK) void k_gemm1(const float* __restrict__ x,
                                               const float* __restrict__ W,
                                               float* __restrict__ h, int n) {
  __shared__ float Ws[128 * 64];
  __shared__ float xs[16][128];
  int tid = threadIdx.x;
  const float4* W4 = (const float4*)W;
  float4* Ws4 = (float4*)Ws;
#pragma unroll
  for (int i = 0; i < 8; i++) Ws4[tid + i * BLK] = W4[tid + i * BLK];
  int row0 = blockIdx.x * 16;
  int nrows = min(16, n - row0);
  const float4* x4 = (const float4*)(x + (size_t)row0 * 128);
  float4* xs4 = (float4*)xs;
  for (int i = tid; i < nrows * 32; i += BLK) xs4[i] = x4[i];
  __syncthreads();
  int col = tid & 63, rg = tid >> 6;  // wave-uniform rg -> xs reads are broadcast
  float acc0 = 0.f, acc1 = 0.f, acc2 = 0.f, acc3 = 0.f;
#pragma unroll 4
  for (int k = 0; k < 128; k++) {
    float w = Ws[k * 64 + col];
    acc0 += xs[rg][k] * w;
    acc1 += xs[rg + 4][k] * w;
    acc2 += xs[rg + 8][k] * w;
    acc3 += xs[rg + 12][k] * w;
  }
  int r = row0 + rg;
  if (r < n)      h[(size_t)r * 64 + col]        = acc0;
  if (r + 4 < n)  h[(size_t)(r + 4) * 64 + col]  = acc1;
  if (r + 8 < n)  h[(size_t)(r + 8) * 64 + col]  = acc2;
  if (r + 12 < n) h[(size_t)(r + 12) * 64 + col] = acc3;
}

// ---------------- self-loop init (also serves as zero-init of accumulators) --

// a1[i][:] = dinv[i]^2 * h1[i][:]   (idx over n*16 float4s)
__global__ __launch_bounds__(BLK) void k_self1(const float* __restrict__ dinv,
                                               const float* __restrict__ h1,
                                               float* __restrict__ a1, int n) {
  int idx = blockIdx.x * BLK + threadIdx.x;
  if (idx >= n * 16) return;
  int node = idx >> 4;
  float di = dinv[node];
  float s = di * di;
  float4 v = ((const float4*)h1)[idx];
  v.x *= s; v.y *= s; v.z *= s; v.w *= s;
  ((float4*)a1)[idx] = v;
}

// out[i][:] = dinv[i]^2 * h2[i][:]  (idx over n*4 float4s)
__global__ __launch_bounds__(BLK) void k_self2(const float* __restrict__ dinv,
                                               const float* __restrict__ h2,
                                               float* __restrict__ out, int n) {
  int idx = blockIdx.x * BLK + threadIdx.x;
  if (idx >= n * 4) return;
  int node = idx >> 2;
  float di = dinv[node];
  float s = di * di;
  float4 v = ((const float4*)h2)[idx];
  v.x *= s; v.y *= s; v.z *= s; v.w *= s;
  ((float4*)out)[idx] = v;
}

// ---------------- edge aggregation (atomic scatter) ----------------

// 64 lanes per edge, 4 edges per block
__global__ __launch_bounds__(BLK) void k_agg1(const int* __restrict__ src,
                                              const int* __restrict__ dst,
                                              const float* __restrict__ norm,
                                              const float* __restrict__ h1,
                                              float* __restrict__ a1, int E) {
  int e = blockIdx.x * 4 + (threadIdx.x >> 6);
  if (e >= E) return;
  int j = threadIdx.x & 63;
  int s = src[e], d = dst[e];
  float w = norm[e];
  unsafeAtomicAdd(&a1[(size_t)d * 64 + j], w * h1[(size_t)s * 64 + j]);
}

// 16 lanes per edge, 16 edges per block
__global__ __launch_bounds__(BLK) void k_agg2(const int* __restrict__ src,
                                              const int* __restrict__ dst,
                                              const float* __restrict__ norm,
                                              const float* __restrict__ h2,
                                              float* __restrict__ out, int E) {
  int e = blockIdx.x * 16 + (threadIdx.x >> 4);
  if (e >= E) return;
  int j = threadIdx.x & 15;
  int s = src[e], d = dst[e];
  float w = norm[e];
  unsafeAtomicAdd(&out[(size_t)d * 16 + j], w * h2[(size_t)s * 16 + j]);
}

// ---------------- GEMM2: h2[n,16] = relu(a1+b1)[n,64] @ W2[64,16] ----------
__global__ __launch_bounds__(BLK) void k_gemm2(const float* __restrict__ a1,
                                               const float* __restrict__ b1,
                                               const float* __restrict__ W2,
                                               float* __restrict__ h2, int n) {
  __shared__ float Ws[64 * 16];
  __shared__ float rs[16][65];  // +1 pad: breaks 4-way bank conflict on rs[r][k]
  int tid = threadIdx.x;
  for (int i = tid; i < 1024; i += BLK) Ws[i] = W2[i];
  int row0 = blockIdx.x * 16;
  int nrows = min(16, n - row0);
  for (int i = tid; i < nrows * 64; i += BLK) {
    int r = i >> 6, c = i & 63;
    float v = a1[(size_t)(row0 + r) * 64 + c] + b1[c];
    rs[r][c] = fmaxf(v, 0.0f);
  }
  __syncthreads();
  int col = tid & 15, r = tid >> 4;
  if (row0 + r < n) {
    float acc = 0.f;
#pragma unroll
    for (int k = 0; k < 64; k++) acc += rs[r][k] * Ws[k * 16 + col];
    h2[(size_t)(row0 + r) * 16 + col] = acc;
  }
}

// ---------------- final: out[i][:] = log_softmax(out[i][:] + b2) ------------
__global__ __launch_bounds__(BLK) void k_lsm(float* __restrict__ out,
                                             const float* __restrict__ b2, int n) {
  int i = blockIdx.x * BLK + threadIdx.x;
  if (i >= n) return;
  float4* o = (float4*)(out + (size_t)i * 16);
  float v[16];
  float4 t0 = o[0], t1 = o[1], t2 = o[2], t3 = o[3];
  v[0] = t0.x; v[1] = t0.y; v[2] = t0.z; v[3] = t0.w;
  v[4] = t1.x; v[5] = t1.y; v[6] = t1.z; v[7] = t1.w;
  v[8] = t2.x; v[9] = t2.y; v[10] = t2.z; v[11] = t2.w;
  v[12] = t3.x; v[13] = t3.y; v[14] = t3.z; v[15] = t3.w;
#pragma unroll
  for (int j = 0; j < 16; j++) v[j] += b2[j];
  float m = v[0];
#pragma unroll
  for (int j = 1; j < 16; j++) m = fmaxf(m, v[j]);
  float s = 0.f;
#pragma unroll
  for (int j = 0; j < 16; j++) s += expf(v[j] - m);
  float ls = m + logf(s);
#pragma unroll
  for (int j = 0; j < 16; j++) v[j] -= ls;
  o[0] = make_float4(v[0], v[1], v[2], v[3]);
  o[1] = make_float4(v[4], v[5], v[6], v[7]);
  o[2] = make_float4(v[8], v[9], v[10], v[11]);
  o[3] = make_float4(v[12], v[13], v[14], v[15]);
}

extern "C" void kernel_launch(void* const* d_in, const int* in_sizes, int n_in,
                              void* d_out, int out_size, void* d_ws, size_t ws_size,
                              hipStream_t stream) {
  const float* x  = (const float*)d_in[0];
  const int*   ei = (const int*)d_in[1];   // int32 [2,E]
  const float* ew = (const float*)d_in[2];
  const float* W1 = (const float*)d_in[3];
  const float* b1 = (const float*)d_in[4];
  const float* W2 = (const float*)d_in[5];
  const float* b2 = (const float*)d_in[6];
  float* out = (float*)d_out;

  int n = in_sizes[0] / 128;
  int E = in_sizes[2];
  const int* src = ei;
  const int* dst = ei + E;

  float* ws   = (float*)d_ws;
  float* deg  = ws;                       // n
  float* dinv = deg + n;                  // n
  float* norm = dinv + n;                 // E
  float* h1   = norm + E;                 // n*64
  float* a1   = h1 + (size_t)n * 64;      // n*64
  float* h2   = a1 + (size_t)n * 64;      // n*16

  int gN = (n + BLK - 1) / BLK;
  int gE = (E + BLK - 1) / BLK;

  k_deg_init<<<gN, BLK, 0, stream>>>(deg, n);
  k_deg_edge<<<gE, BLK, 0, stream>>>(ew, dst, deg, E);
  k_dinv<<<gN, BLK, 0, stream>>>(deg, dinv, n);
  k_norm<<<gE, BLK, 0, stream>>>(src, dst, ew, dinv, norm, E);

  k_gemm1<<<(n + 15) / 16, BLK, 0, stream>>>(x, W1, h1, n);
  k_self1<<<(n * 16 + BLK - 1) / BLK, BLK, 0, stream>>>(dinv, h1, a1, n);
  k_agg1<<<(E + 3) / 4, BLK, 0, stream>>>(src, dst, norm, h1, a1, E);

  k_gemm2<<<(n + 15) / 16, BLK, 0, stream>>>(a1, b1, W2, h2, n);
  k_self2<<<(n * 4 + BLK - 1) / BLK, BLK, 0, stream>>>(dinv, h2, out, n);
  k_agg2<<<(E + 15) / 16, BLK, 0, stream>>>(src, dst, norm, h2, out, E);

  k_lsm<<<gN, BLK, 0, stream>>>(out, b2, n);
}

// Round 3
// 635.461 us; speedup vs baseline: 1.1120x; 1.1120x over previous
//
#include <hip/hip_runtime.h>
#include <cstdint>

#define BLK 256
#define SC_ITEMS 8
#define SC_CHUNK (BLK * SC_ITEMS)  // 2048 elements per scan block

// ---------------- init: deg = 1 (self-loop), cnt = 0 ----------------
__global__ __launch_bounds__(BLK) void k_init(float* __restrict__ deg,
                                              int* __restrict__ cnt, int n) {
  int i = blockIdx.x * BLK + threadIdx.x;
  if (i < n) { deg[i] = 1.0f; cnt[i] = 0; }
}

// ---------------- histogram: weighted degree + integer counts ----------------
__global__ __launch_bounds__(BLK) void k_hist(const int* __restrict__ dst,
                                              const float* __restrict__ ew,
                                              float* __restrict__ deg,
                                              int* __restrict__ cnt, int n, int E) {
  int e = blockIdx.x * BLK + threadIdx.x;
  if (e < E) {
    int d = dst[e];
    if ((unsigned)d < (unsigned)n) {
      unsafeAtomicAdd(&deg[d], ew[e]);
      atomicAdd(&cnt[d], 1);
    }
  }
}

__global__ __launch_bounds__(BLK) void k_dinv(const float* __restrict__ deg,
                                              float* __restrict__ dinv, int n) {
  int i = blockIdx.x * BLK + threadIdx.x;
  if (i < n) {
    float d = deg[i];
    dinv[i] = d > 0.0f ? rsqrtf(d) : 0.0f;
  }
}

// ---------------- scan: rs = exclusive_scan(cnt), OUT OF PLACE ----------------
__global__ __launch_bounds__(BLK) void k_scan1(const int* __restrict__ cnt,
                                               int* __restrict__ bs, int n) {
  __shared__ int sd[BLK];
  int tid = threadIdx.x;
  int base = blockIdx.x * SC_CHUNK + tid * SC_ITEMS;
  int t = 0;
#pragma unroll
  for (int j = 0; j < SC_ITEMS; j++) {
    int i = base + j;
    t += (i < n) ? cnt[i] : 0;
  }
  sd[tid] = t;
  __syncthreads();
  for (int off = BLK / 2; off > 0; off >>= 1) {
    if (tid < off) sd[tid] += sd[tid + off];
    __syncthreads();
  }
  if (tid == 0) bs[blockIdx.x] = sd[0];
}

__global__ __launch_bounds__(BLK) void k_scan2(int* __restrict__ bs, int nb) {
  __shared__ int sd[BLK];
  int tid = threadIdx.x;
  int t = (tid < nb) ? bs[tid] : 0;
  sd[tid] = t;
  __syncthreads();
  int run = t;
  for (int off = 1; off < BLK; off <<= 1) {
    int u = (tid >= off) ? sd[tid - off] : 0;
    __syncthreads();
    run += u;
    sd[tid] = run;
    __syncthreads();
  }
  if (tid < nb) bs[tid] = run - t;  // exclusive block offsets
}

__global__ __launch_bounds__(BLK) void k_scan3(const int* __restrict__ cnt,
                                               const int* __restrict__ bs,
                                               int* __restrict__ rs, int n, int E) {
  __shared__ int sd[BLK];
  int tid = threadIdx.x;
  int base = blockIdx.x * SC_CHUNK + tid * SC_ITEMS;
  int v[SC_ITEMS];
  int t = 0;
#pragma unroll
  for (int j = 0; j < SC_ITEMS; j++) {
    int i = base + j;
    v[j] = (i < n) ? cnt[i] : 0;
    t += v[j];
  }
  sd[tid] = t;
  __syncthreads();
  int run = t;
  for (int off = 1; off < BLK; off <<= 1) {
    int u = (tid >= off) ? sd[tid - off] : 0;
    __syncthreads();
    run += u;
    sd[tid] = run;
    __syncthreads();
  }
  int excl = run - t + bs[blockIdx.x];
#pragma unroll
  for (int j = 0; j < SC_ITEMS; j++) {
    int i = base + j;
    if (i < n) { rs[i] = excl; excl += v[j]; }
  }
  if (blockIdx.x == 0 && tid == 0) rs[n] = E;
}

// cursor copy: cur[i] = rs[i]
__global__ __launch_bounds__(BLK) void k_cur(const int* __restrict__ rs,
                                             int* __restrict__ cur, int n) {
  int i = blockIdx.x * BLK + threadIdx.x;
  if (i < n) cur[i] = rs[i];
}

// ---------------- scatter edges into CSR order: es[p] = {src, norm} ---------
__global__ __launch_bounds__(BLK) void k_scatter(const int* __restrict__ src,
                                                 const int* __restrict__ dst,
                                                 const float* __restrict__ ew,
                                                 const float* __restrict__ dinv,
                                                 int* __restrict__ cur,
                                                 int2* __restrict__ es, int n, int E) {
  int e = blockIdx.x * BLK + threadIdx.x;
  if (e >= E) return;
  int s = src[e], d = dst[e];
  if ((unsigned)s >= (unsigned)n || (unsigned)d >= (unsigned)n) return;
  float w = dinv[s] * ew[e] * dinv[d];
  int p = atomicAdd(&cur[d], 1);
  if ((unsigned)p < (unsigned)E) es[p] = make_int2(s, __float_as_int(w));
}

// ---------------- GEMM1: h1[n,64] = x[n,128] @ W1[128,64] ----------------
__global__ __launch_bounds__(BLK) void k_gemm1(const float* __restrict__ x,
                                               const float* __restrict__ W,
                                               float* __restrict__ h, int n) {
  __shared__ float Ws[128 * 64];
  __shared__ float xs[16][128];
  int tid = threadIdx.x;
  const float4* W4 = (const float4*)W;
  float4* Ws4 = (float4*)Ws;
#pragma unroll
  for (int i = 0; i < 8; i++) Ws4[tid + i * BLK] = W4[tid + i * BLK];
  int row0 = blockIdx.x * 16;
  int nrows = min(16, n - row0);
  const float4* x4 = (const float4*)(x + (size_t)row0 * 128);
  float4* xs4 = (float4*)xs;
  for (int i = tid; i < nrows * 32; i += BLK) xs4[i] = x4[i];
  __syncthreads();
  int col = tid & 63, rg = tid >> 6;  // wave-uniform rg -> xs reads broadcast
  float acc0 = 0.f, acc1 = 0.f, acc2 = 0.f, acc3 = 0.f;
#pragma unroll 4
  for (int k = 0; k < 128; k++) {
    float w = Ws[k * 64 + col];
    acc0 += xs[rg][k] * w;
    acc1 += xs[rg + 4][k] * w;
    acc2 += xs[rg + 8][k] * w;
    acc3 += xs[rg + 12][k] * w;
  }
  int r = row0 + rg;
  if (r < n)      h[(size_t)r * 64 + col]        = acc0;
  if (r + 4 < n)  h[(size_t)(r + 4) * 64 + col]  = acc1;
  if (r + 8 < n)  h[(size_t)(r + 8) * 64 + col]  = acc2;
  if (r + 12 < n) h[(size_t)(r + 12) * 64 + col] = acc3;
}

// ---------------- fused layer-1 aggregate + bias + ReLU + GEMM2 -------------
// One wave per node: lane k holds a1[v][k]; then h2[v][c] via shfl contraction.
__global__ __launch_bounds__(BLK) void k_agg1f(const float* __restrict__ dinv,
                                               const int* __restrict__ rs,
                                               const int2* __restrict__ es,
                                               const float* __restrict__ h1,
                                               const float* __restrict__ b1,
                                               const float* __restrict__ W2,
                                               float* __restrict__ h2, int n, int E) {
  __shared__ float W2s[64 * 16];
  int tid = threadIdx.x;
  for (int i = tid; i < 1024; i += BLK) W2s[i] = W2[i];
  int v = blockIdx.x * 4 + (tid >> 6);
  int lane = tid & 63;
  float acc = 0.f;
  if (v < n) {
    int start = rs[v], end = rs[v + 1];
    start = max(0, min(start, E));
    end = max(start, min(end, E));
    float di = dinv[v];
    acc = di * di * h1[(size_t)v * 64 + lane];
    for (int i = start; i < end; i++) {
      int2 e = es[i];
      if ((unsigned)e.x < (unsigned)n)
        acc += __int_as_float(e.y) * h1[(size_t)e.x * 64 + lane];
    }
  }
  float r = fmaxf(acc + b1[lane], 0.f);
  __syncthreads();  // W2s ready (all threads reach: no early returns above)
  int q = lane >> 4, c = lane & 15;
  float p = 0.f;
#pragma unroll
  for (int j = 0; j < 16; j++) {
    float rv = __shfl(r, 16 * q + j, 64);
    p += rv * W2s[(16 * q + j) * 16 + c];
  }
  p += __shfl_xor(p, 16, 64);
  p += __shfl_xor(p, 32, 64);
  if (v < n && lane < 16) h2[(size_t)v * 16 + lane] = p;
}

// ---------------- fused layer-2 aggregate + bias + log_softmax --------------
__global__ __launch_bounds__(BLK) void k_agg2f(const float* __restrict__ dinv,
                                               const int* __restrict__ rs,
                                               const int2* __restrict__ es,
                                               const float* __restrict__ h2,
                                               const float* __restrict__ b2,
                                               float* __restrict__ out, int n, int E) {
  int tid = threadIdx.x;
  int v = blockIdx.x * 16 + (tid >> 4);
  int j = tid & 15;
  if (v >= n) return;
  int start = rs[v], end = rs[v + 1];
  start = max(0, min(start, E));
  end = max(start, min(end, E));
  float di = dinv[v];
  float acc = di * di * h2[(size_t)v * 16 + j];
  for (int i = start; i < end; i++) {
    int2 e = es[i];
    if ((unsigned)e.x < (unsigned)n)
      acc += __int_as_float(e.y) * h2[(size_t)e.x * 16 + j];
  }
  acc += b2[j];
  float m = acc;
  m = fmaxf(m, __shfl_xor(m, 1, 64));
  m = fmaxf(m, __shfl_xor(m, 2, 64));
  m = fmaxf(m, __shfl_xor(m, 4, 64));
  m = fmaxf(m, __shfl_xor(m, 8, 64));
  float ex = expf(acc - m);
  float s = ex;
  s += __shfl_xor(s, 1, 64);
  s += __shfl_xor(s, 2, 64);
  s += __shfl_xor(s, 4, 64);
  s += __shfl_xor(s, 8, 64);
  out[(size_t)v * 16 + j] = acc - m - logf(s);
}

extern "C" void kernel_launch(void* const* d_in, const int* in_sizes, int n_in,
                              void* d_out, int out_size, void* d_ws, size_t ws_size,
                              hipStream_t stream) {
  const float* x  = (const float*)d_in[0];
  const int*   ei = (const int*)d_in[1];   // int32 [2,E]
  const float* ew = (const float*)d_in[2];
  const float* W1 = (const float*)d_in[3];
  const float* b1 = (const float*)d_in[4];
  const float* W2 = (const float*)d_in[5];
  const float* b2 = (const float*)d_in[6];
  float* out = (float*)d_out;

  int n = in_sizes[0] / 128;
  int E = in_sizes[2];
  const int* src = ei;
  const int* dst = ei + E;

  // workspace layout (4B units), NO aliasing:
  // deg[n] | dinv[n] | cnt[n] | rs[n+1] | cur[n] | bs[256] | es[2E] | h1[64n] | h2[16n]
  float* ws   = (float*)d_ws;
  float* deg  = ws;                              // n
  float* dinv = deg + n;                         // n
  int*   cnt  = (int*)(dinv + n);                // n
  int*   rs   = cnt + n;                         // n+1
  int*   cur  = rs + n + 1;                      // n
  int*   bs   = cur + n;                         // 256
  int2*  es   = (int2*)(bs + 256);               // E records (2E ints)
  float* h1   = (float*)(es + (size_t)E);        // 64n
  float* h2   = h1 + 64 * (size_t)n;             // 16n

  int gN = (n + BLK - 1) / BLK;
  int gE = (E + BLK - 1) / BLK;
  int NB = (n + SC_CHUNK - 1) / SC_CHUNK;        // 49 for n=100k (must be <= 256)

  k_init<<<gN, BLK, 0, stream>>>(deg, cnt, n);
  k_hist<<<gE, BLK, 0, stream>>>(dst, ew, deg, cnt, n, E);
  k_dinv<<<gN, BLK, 0, stream>>>(deg, dinv, n);
  k_scan1<<<NB, BLK, 0, stream>>>(cnt, bs, n);
  k_scan2<<<1, BLK, 0, stream>>>(bs, NB);
  k_scan3<<<NB, BLK, 0, stream>>>(cnt, bs, rs, n, E);
  k_cur<<<gN, BLK, 0, stream>>>(rs, cur, n);
  k_scatter<<<gE, BLK, 0, stream>>>(src, dst, ew, dinv, cur, es, n, E);

  k_gemm1<<<(n + 15) / 16, BLK, 0, stream>>>(x, W1, h1, n);
  k_agg1f<<<(n + 3) / 4, BLK, 0, stream>>>(dinv, rs, es, h1, b1, W2, h2, n, E);
  k_agg2f<<<(n + 15) / 16, BLK, 0, stream>>>(dinv, rs, es, h2, b2, out, n, E);
}

// Round 4
// 517.293 us; speedup vs baseline: 1.3661x; 1.2284x over previous
//
#include <hip/hip_runtime.h>
#include <cstdint>

#define BLK 256
#define SC_ITEMS 8
#define SC_CHUNK (BLK * SC_ITEMS)  // 2048 elements per scan block

// ---------------- init: deg = 1 (self-loop), cnt = 0 ----------------
__global__ __launch_bounds__(BLK) void k_init(float* __restrict__ deg,
                                              int* __restrict__ cnt, int n) {
  int i = blockIdx.x * BLK + threadIdx.x;
  if (i < n) { deg[i] = 1.0f; cnt[i] = 0; }
}

// ---------------- histogram: weighted degree + integer counts ----------------
__global__ __launch_bounds__(BLK) void k_hist(const int* __restrict__ dst,
                                              const float* __restrict__ ew,
                                              float* __restrict__ deg,
                                              int* __restrict__ cnt, int n, int E) {
  int e = blockIdx.x * BLK + threadIdx.x;
  if (e < E) {
    int d = dst[e];
    if ((unsigned)d < (unsigned)n) {
      unsafeAtomicAdd(&deg[d], ew[e]);
      atomicAdd(&cnt[d], 1);
    }
  }
}

__global__ __launch_bounds__(BLK) void k_dinv(const float* __restrict__ deg,
                                              float* __restrict__ dinv, int n) {
  int i = blockIdx.x * BLK + threadIdx.x;
  if (i < n) {
    float d = deg[i];
    dinv[i] = d > 0.0f ? rsqrtf(d) : 0.0f;
  }
}

// ---------------- scan: rs = exclusive_scan(cnt), OUT OF PLACE ----------------
__global__ __launch_bounds__(BLK) void k_scan1(const int* __restrict__ cnt,
                                               int* __restrict__ bs, int n) {
  __shared__ int sd[BLK];
  int tid = threadIdx.x;
  int base = blockIdx.x * SC_CHUNK + tid * SC_ITEMS;
  int t = 0;
#pragma unroll
  for (int j = 0; j < SC_ITEMS; j++) {
    int i = base + j;
    t += (i < n) ? cnt[i] : 0;
  }
  sd[tid] = t;
  __syncthreads();
  for (int off = BLK / 2; off > 0; off >>= 1) {
    if (tid < off) sd[tid] += sd[tid + off];
    __syncthreads();
  }
  if (tid == 0) bs[blockIdx.x] = sd[0];
}

__global__ __launch_bounds__(BLK) void k_scan2(int* __restrict__ bs, int nb) {
  __shared__ int sd[BLK];
  int tid = threadIdx.x;
  int t = (tid < nb) ? bs[tid] : 0;
  sd[tid] = t;
  __syncthreads();
  int run = t;
  for (int off = 1; off < BLK; off <<= 1) {
    int u = (tid >= off) ? sd[tid - off] : 0;
    __syncthreads();
    run += u;
    sd[tid] = run;
    __syncthreads();
  }
  if (tid < nb) bs[tid] = run - t;  // exclusive block offsets
}

__global__ __launch_bounds__(BLK) void k_scan3(const int* __restrict__ cnt,
                                               const int* __restrict__ bs,
                                               int* __restrict__ rs, int n, int E) {
  __shared__ int sd[BLK];
  int tid = threadIdx.x;
  int base = blockIdx.x * SC_CHUNK + tid * SC_ITEMS;
  int v[SC_ITEMS];
  int t = 0;
#pragma unroll
  for (int j = 0; j < SC_ITEMS; j++) {
    int i = base + j;
    v[j] = (i < n) ? cnt[i] : 0;
    t += v[j];
  }
  sd[tid] = t;
  __syncthreads();
  int run = t;
  for (int off = 1; off < BLK; off <<= 1) {
    int u = (tid >= off) ? sd[tid - off] : 0;
    __syncthreads();
    run += u;
    sd[tid] = run;
    __syncthreads();
  }
  int excl = run - t + bs[blockIdx.x];
#pragma unroll
  for (int j = 0; j < SC_ITEMS; j++) {
    int i = base + j;
    if (i < n) { rs[i] = excl; excl += v[j]; }
  }
  if (blockIdx.x == 0 && tid == 0) rs[n] = E;
}

// cursor copy: cur[i] = rs[i]
__global__ __launch_bounds__(BLK) void k_cur(const int* __restrict__ rs,
                                             int* __restrict__ cur, int n) {
  int i = blockIdx.x * BLK + threadIdx.x;
  if (i < n) cur[i] = rs[i];
}

// ---------------- scatter edges into CSR order: es[p] = {src, norm} ---------
__global__ __launch_bounds__(BLK) void k_scatter(const int* __restrict__ src,
                                                 const int* __restrict__ dst,
                                                 const float* __restrict__ ew,
                                                 const float* __restrict__ dinv,
                                                 int* __restrict__ cur,
                                                 int2* __restrict__ es, int n, int E) {
  int e = blockIdx.x * BLK + threadIdx.x;
  if (e >= E) return;
  int s = src[e], d = dst[e];
  if ((unsigned)s >= (unsigned)n || (unsigned)d >= (unsigned)n) return;
  float w = dinv[s] * ew[e] * dinv[d];
  int p = atomicAdd(&cur[d], 1);
  if ((unsigned)p < (unsigned)E) es[p] = make_int2(s, __float_as_int(w));
}

// ---------------- GEMM1: h1[n,64] = x[n,128] @ W1[128,64] ----------------
__global__ __launch_bounds__(BLK) void k_gemm1(const float* __restrict__ x,
                                               const float* __restrict__ W,
                                               float* __restrict__ h, int n) {
  __shared__ float Ws[128 * 64];
  __shared__ float xs[16][128];
  int tid = threadIdx.x;
  const float4* W4 = (const float4*)W;
  float4* Ws4 = (float4*)Ws;
#pragma unroll
  for (int i = 0; i < 8; i++) Ws4[tid + i * BLK] = W4[tid + i * BLK];
  int row0 = blockIdx.x * 16;
  int nrows = min(16, n - row0);
  const float4* x4 = (const float4*)(x + (size_t)row0 * 128);
  float4* xs4 = (float4*)xs;
  for (int i = tid; i < nrows * 32; i += BLK) xs4[i] = x4[i];
  __syncthreads();
  int col = tid & 63, rg = tid >> 6;  // wave-uniform rg -> xs reads broadcast
  float acc0 = 0.f, acc1 = 0.f, acc2 = 0.f, acc3 = 0.f;
#pragma unroll 4
  for (int k = 0; k < 128; k++) {
    float w = Ws[k * 64 + col];
    acc0 += xs[rg][k] * w;
    acc1 += xs[rg + 4][k] * w;
    acc2 += xs[rg + 8][k] * w;
    acc3 += xs[rg + 12][k] * w;
  }
  int r = row0 + rg;
  if (r < n)      h[(size_t)r * 64 + col]        = acc0;
  if (r + 4 < n)  h[(size_t)(r + 4) * 64 + col]  = acc1;
  if (r + 8 < n)  h[(size_t)(r + 8) * 64 + col]  = acc2;
  if (r + 12 < n) h[(size_t)(r + 12) * 64 + col] = acc3;
}

// ---------------- fused layer-1 aggregate + bias + ReLU + GEMM2 -------------
// One wave per node: lane k holds a1[v][k]; then h2[v][c] via shfl contraction.
// Unroll-8 main loop: 8 independent h1 gathers in flight (latency hiding).
__global__ __launch_bounds__(BLK) void k_agg1f(const float* __restrict__ dinv,
                                               const int* __restrict__ rs,
                                               const int2* __restrict__ es,
                                               const float* __restrict__ h1,
                                               const float* __restrict__ b1,
                                               const float* __restrict__ W2,
                                               float* __restrict__ h2, int n, int E) {
  __shared__ float W2s[64 * 16];
  int tid = threadIdx.x;
  for (int i = tid; i < 1024; i += BLK) W2s[i] = W2[i];
  int v = blockIdx.x * 4 + (tid >> 6);
  int lane = tid & 63;
  float acc = 0.f;
  if (v < n) {
    int start = rs[v], end = rs[v + 1];
    start = max(0, min(start, E));
    end = max(start, min(end, E));
    float di = dinv[v];
    acc = di * di * h1[(size_t)v * 64 + lane];
    int i = start;
    for (; i + 8 <= end; i += 8) {
      int2 e0 = es[i],     e1 = es[i + 1], e2 = es[i + 2], e3 = es[i + 3];
      int2 e4 = es[i + 4], e5 = es[i + 5], e6 = es[i + 6], e7 = es[i + 7];
      float g0 = h1[(size_t)e0.x * 64 + lane];
      float g1 = h1[(size_t)e1.x * 64 + lane];
      float g2 = h1[(size_t)e2.x * 64 + lane];
      float g3 = h1[(size_t)e3.x * 64 + lane];
      float g4 = h1[(size_t)e4.x * 64 + lane];
      float g5 = h1[(size_t)e5.x * 64 + lane];
      float g6 = h1[(size_t)e6.x * 64 + lane];
      float g7 = h1[(size_t)e7.x * 64 + lane];
      acc += __int_as_float(e0.y) * g0;
      acc += __int_as_float(e1.y) * g1;
      acc += __int_as_float(e2.y) * g2;
      acc += __int_as_float(e3.y) * g3;
      acc += __int_as_float(e4.y) * g4;
      acc += __int_as_float(e5.y) * g5;
      acc += __int_as_float(e6.y) * g6;
      acc += __int_as_float(e7.y) * g7;
    }
    for (; i + 2 <= end; i += 2) {
      int2 e0 = es[i], e1 = es[i + 1];
      float g0 = h1[(size_t)e0.x * 64 + lane];
      float g1 = h1[(size_t)e1.x * 64 + lane];
      acc += __int_as_float(e0.y) * g0;
      acc += __int_as_float(e1.y) * g1;
    }
    if (i < end) {
      int2 e = es[i];
      acc += __int_as_float(e.y) * h1[(size_t)e.x * 64 + lane];
    }
  }
  float r = fmaxf(acc + b1[lane], 0.f);
  __syncthreads();  // W2s ready (all threads reach: no early returns above)
  int q = lane >> 4, c = lane & 15;
  float p = 0.f;
#pragma unroll
  for (int j = 0; j < 16; j++) {
    float rv = __shfl(r, 16 * q + j, 64);
    p += rv * W2s[(16 * q + j) * 16 + c];
  }
  p += __shfl_xor(p, 16, 64);
  p += __shfl_xor(p, 32, 64);
  if (v < n && lane < 16) h2[(size_t)v * 16 + lane] = p;
}

// ---------------- fused layer-2 aggregate + bias + log_softmax --------------
// 16-lane group per node; unroll-4 for gather MLP.
__global__ __launch_bounds__(BLK) void k_agg2f(const float* __restrict__ dinv,
                                               const int* __restrict__ rs,
                                               const int2* __restrict__ es,
                                               const float* __restrict__ h2,
                                               const float* __restrict__ b2,
                                               float* __restrict__ out, int n, int E) {
  int tid = threadIdx.x;
  int v = blockIdx.x * 16 + (tid >> 4);
  int j = tid & 15;
  if (v >= n) return;
  int start = rs[v], end = rs[v + 1];
  start = max(0, min(start, E));
  end = max(start, min(end, E));
  float di = dinv[v];
  float acc = di * di * h2[(size_t)v * 16 + j];
  int i = start;
  for (; i + 4 <= end; i += 4) {
    int2 e0 = es[i], e1 = es[i + 1], e2 = es[i + 2], e3 = es[i + 3];
    float g0 = h2[(size_t)e0.x * 16 + j];
    float g1 = h2[(size_t)e1.x * 16 + j];
    float g2 = h2[(size_t)e2.x * 16 + j];
    float g3 = h2[(size_t)e3.x * 16 + j];
    acc += __int_as_float(e0.y) * g0;
    acc += __int_as_float(e1.y) * g1;
    acc += __int_as_float(e2.y) * g2;
    acc += __int_as_float(e3.y) * g3;
  }
  for (; i < end; i++) {
    int2 e = es[i];
    acc += __int_as_float(e.y) * h2[(size_t)e.x * 16 + j];
  }
  acc += b2[j];
  float m = acc;
  m = fmaxf(m, __shfl_xor(m, 1, 64));
  m = fmaxf(m, __shfl_xor(m, 2, 64));
  m = fmaxf(m, __shfl_xor(m, 4, 64));
  m = fmaxf(m, __shfl_xor(m, 8, 64));
  float ex = expf(acc - m);
  float s = ex;
  s += __shfl_xor(s, 1, 64);
  s += __shfl_xor(s, 2, 64);
  s += __shfl_xor(s, 4, 64);
  s += __shfl_xor(s, 8, 64);
  out[(size_t)v * 16 + j] = acc - m - logf(s);
}

extern "C" void kernel_launch(void* const* d_in, const int* in_sizes, int n_in,
                              void* d_out, int out_size, void* d_ws, size_t ws_size,
                              hipStream_t stream) {
  const float* x  = (const float*)d_in[0];
  const int*   ei = (const int*)d_in[1];   // int32 [2,E]
  const float* ew = (const float*)d_in[2];
  const float* W1 = (const float*)d_in[3];
  const float* b1 = (const float*)d_in[4];
  const float* W2 = (const float*)d_in[5];
  const float* b2 = (const float*)d_in[6];
  float* out = (float*)d_out;

  int n = in_sizes[0] / 128;
  int E = in_sizes[2];
  const int* src = ei;
  const int* dst = ei + E;

  // workspace layout (4B units), NO aliasing:
  // deg[n] | dinv[n] | cnt[n] | rs[n+1] | cur[n] | bs[256] | es[2E] | h1[64n] | h2[16n]
  float* ws   = (float*)d_ws;
  float* deg  = ws;                              // n
  float* dinv = deg + n;                         // n
  int*   cnt  = (int*)(dinv + n);                // n
  int*   rs   = cnt + n;                         // n+1
  int*   cur  = rs + n + 1;                      // n
  int*   bs   = cur + n;                         // 256
  int2*  es   = (int2*)(bs + 256);               // E records (2E ints)
  float* h1   = (float*)(es + (size_t)E);        // 64n
  float* h2   = h1 + 64 * (size_t)n;             // 16n

  int gN = (n + BLK - 1) / BLK;
  int gE = (E + BLK - 1) / BLK;
  int NB = (n + SC_CHUNK - 1) / SC_CHUNK;        // 49 for n=100k (must be <= 256)

  k_init<<<gN, BLK, 0, stream>>>(deg, cnt, n);
  k_hist<<<gE, BLK, 0, stream>>>(dst, ew, deg, cnt, n, E);
  k_dinv<<<gN, BLK, 0, stream>>>(deg, dinv, n);
  k_scan1<<<NB, BLK, 0, stream>>>(cnt, bs, n);
  k_scan2<<<1, BLK, 0, stream>>>(bs, NB);
  k_scan3<<<NB, BLK, 0, stream>>>(cnt, bs, rs, n, E);
  k_cur<<<gN, BLK, 0, stream>>>(rs, cur, n);
  k_scatter<<<gE, BLK, 0, stream>>>(src, dst, ew, dinv, cur, es, n, E);

  k_gemm1<<<(n + 15) / 16, BLK, 0, stream>>>(x, W1, h1, n);
  k_agg1f<<<(n + 3) / 4, BLK, 0, stream>>>(dinv, rs, es, h1, b1, W2, h2, n, E);
  k_agg2f<<<(n + 15) / 16, BLK, 0, stream>>>(dinv, rs, es, h2, b2, out, n, E);
}

// Round 6
// 457.330 us; speedup vs baseline: 1.5452x; 1.1311x over previous
//
#include <hip/hip_runtime.h>
#include <cstdint>

#define BLK 256
#define SC_ITEMS 8
#define SC_CHUNK (BLK * SC_ITEMS)  // 2048 elements per scan block

__device__ inline unsigned short f2bf(float f) {  // RNE
  unsigned u = __float_as_uint(f);
  return (unsigned short)((u + 0x7FFF + ((u >> 16) & 1)) >> 16);
}
__device__ inline float bfsel(unsigned u, int hb) {  // decode half hb of bf16x2
  return __uint_as_float(hb ? (u & 0xFFFF0000u) : (u << 16));
}

// ---------------- init: cnt = 0 ----------------
__global__ __launch_bounds__(BLK) void k_init(int* __restrict__ cnt, int n) {
  int i = blockIdx.x * BLK + threadIdx.x;
  if (i < n) cnt[i] = 0;
}

// ---------------- histogram: integer in-degree counts (ONE atomic/edge) -----
__global__ __launch_bounds__(BLK) void k_hist(const int* __restrict__ dst,
                                              int* __restrict__ cnt, int n, int E) {
  int e = blockIdx.x * BLK + threadIdx.x;
  if (e < E) {
    int d = dst[e];
    if ((unsigned)d < (unsigned)n) atomicAdd(&cnt[d], 1);
  }
}

// ---------------- scan: rs = exclusive_scan(cnt), OUT OF PLACE ----------------
__global__ __launch_bounds__(BLK) void k_scan1(const int* __restrict__ cnt,
                                               int* __restrict__ bs, int n) {
  __shared__ int sd[BLK];
  int tid = threadIdx.x;
  int base = blockIdx.x * SC_CHUNK + tid * SC_ITEMS;
  int t = 0;
#pragma unroll
  for (int j = 0; j < SC_ITEMS; j++) {
    int i = base + j;
    t += (i < n) ? cnt[i] : 0;
  }
  sd[tid] = t;
  __syncthreads();
  for (int off = BLK / 2; off > 0; off >>= 1) {
    if (tid < off) sd[tid] += sd[tid + off];
    __syncthreads();
  }
  if (tid == 0) bs[blockIdx.x] = sd[0];
}

__global__ __launch_bounds__(BLK) void k_scan2(int* __restrict__ bs, int nb) {
  __shared__ int sd[BLK];
  int tid = threadIdx.x;
  int t = (tid < nb) ? bs[tid] : 0;
  sd[tid] = t;
  __syncthreads();
  int run = t;
  for (int off = 1; off < BLK; off <<= 1) {
    int u = (tid >= off) ? sd[tid - off] : 0;
    __syncthreads();
    run += u;
    sd[tid] = run;
    __syncthreads();
  }
  if (tid < nb) bs[tid] = run - t;  // exclusive block offsets
}

__global__ __launch_bounds__(BLK) void k_scan3(const int* __restrict__ cnt,
                                               const int* __restrict__ bs,
                                               int* __restrict__ rs, int n, int E) {
  __shared__ int sd[BLK];
  int tid = threadIdx.x;
  int base = blockIdx.x * SC_CHUNK + tid * SC_ITEMS;
  int v[SC_ITEMS];
  int t = 0;
#pragma unroll
  for (int j = 0; j < SC_ITEMS; j++) {
    int i = base + j;
    v[j] = (i < n) ? cnt[i] : 0;
    t += v[j];
  }
  sd[tid] = t;
  __syncthreads();
  int run = t;
  for (int off = 1; off < BLK; off <<= 1) {
    int u = (tid >= off) ? sd[tid - off] : 0;
    __syncthreads();
    run += u;
    sd[tid] = run;
    __syncthreads();
  }
  int excl = run - t + bs[blockIdx.x];
#pragma unroll
  for (int j = 0; j < SC_ITEMS; j++) {
    int i = base + j;
    if (i < n) { rs[i] = excl; excl += v[j]; }
  }
  if (blockIdx.x == 0 && tid == 0) rs[n] = E;
}

// cursor copy: cur[i] = rs[i]   (dedicated kernel — proven pipeline shape)
__global__ __launch_bounds__(BLK) void k_cur(const int* __restrict__ rs,
                                             int* __restrict__ cur, int n) {
  int i = blockIdx.x * BLK + threadIdx.x;
  if (i < n) cur[i] = rs[i];
}

// ---------------- scatter edges into CSR order: es[p] = {src, RAW ew} -------
__global__ __launch_bounds__(BLK) void k_scatter(const int* __restrict__ src,
                                                 const int* __restrict__ dst,
                                                 const float* __restrict__ ew,
                                                 int* __restrict__ cur,
                                                 int2* __restrict__ es, int n, int E) {
  int e = blockIdx.x * BLK + threadIdx.x;
  if (e >= E) return;
  int s = src[e], d = dst[e];
  if ((unsigned)s >= (unsigned)n || (unsigned)d >= (unsigned)n) return;
  int p = atomicAdd(&cur[d], 1);
  if ((unsigned)p < (unsigned)E) es[p] = make_int2(s, __float_as_int(ew[e]));
}

// ---------------- deg row-sum (contiguous, no atomics) + dinv ----------------
// 16-lane group per node.
__global__ __launch_bounds__(BLK) void k_degdinv(const int* __restrict__ rs,
                                                 const int2* __restrict__ es,
                                                 float* __restrict__ dinv, int n, int E) {
  int tid = threadIdx.x;
  int v = blockIdx.x * 16 + (tid >> 4);
  int j = tid & 15;
  if (v >= n) return;
  int start = rs[v], end = rs[v + 1];
  start = max(0, min(start, E));
  end = max(start, min(end, E));
  float t = 0.f;
  for (int i = start + j; i < end; i += 16) t += __int_as_float(es[i].y);
  t += __shfl_xor(t, 1, 64);
  t += __shfl_xor(t, 2, 64);
  t += __shfl_xor(t, 4, 64);
  t += __shfl_xor(t, 8, 64);
  if (j == 0) {
    float deg = 1.0f + t;
    dinv[v] = deg > 0.f ? rsqrtf(deg) : 0.f;
  }
}

// ---------------- GEMM1: h1s[n,64](bf16x2) = dinv * (x[n,128] @ W1[128,64]) --
__global__ __launch_bounds__(BLK) void k_gemm1(const float* __restrict__ x,
                                               const float* __restrict__ W,
                                               const float* __restrict__ dinv,
                                               unsigned* __restrict__ h1s, int n) {
  __shared__ float Ws[128 * 64];
  __shared__ float xs[16][128];
  int tid = threadIdx.x;
  const float4* W4 = (const float4*)W;
  float4* Ws4 = (float4*)Ws;
#pragma unroll
  for (int i = 0; i < 8; i++) Ws4[tid + i * BLK] = W4[tid + i * BLK];
  int row0 = blockIdx.x * 16;
  int nrows = min(16, n - row0);
  const float4* x4 = (const float4*)(x + (size_t)row0 * 128);
  float4* xs4 = (float4*)xs;
  for (int i = tid; i < nrows * 32; i += BLK) xs4[i] = x4[i];
  __syncthreads();
  int col = tid & 63, rg = tid >> 6;  // wave-uniform rg -> xs reads broadcast
  float acc0 = 0.f, acc1 = 0.f, acc2 = 0.f, acc3 = 0.f;
#pragma unroll 4
  for (int k = 0; k < 128; k++) {
    float w = Ws[k * 64 + col];
    acc0 += xs[rg][k] * w;
    acc1 += xs[rg + 4][k] * w;
    acc2 += xs[rg + 8][k] * w;
    acc3 += xs[rg + 12][k] * w;
  }
  // scale by dinv[row], pack bf16x2 (even col packs {col, col+1})
  int r = row0 + rg;
  int rc0 = min(r, n - 1), rc1 = min(r + 4, n - 1),
      rc2 = min(r + 8, n - 1), rc3 = min(r + 12, n - 1);
  float v0 = acc0 * dinv[rc0], v1 = acc1 * dinv[rc1],
        v2 = acc2 * dinv[rc2], v3 = acc3 * dinv[rc3];
  float p0 = __shfl_xor(v0, 1, 64), p1 = __shfl_xor(v1, 1, 64),
        p2 = __shfl_xor(v2, 1, 64), p3 = __shfl_xor(v3, 1, 64);
  if ((col & 1) == 0) {
    int dw = col >> 1;
    unsigned u0 = (unsigned)f2bf(v0) | ((unsigned)f2bf(p0) << 16);
    unsigned u1 = (unsigned)f2bf(v1) | ((unsigned)f2bf(p1) << 16);
    unsigned u2 = (unsigned)f2bf(v2) | ((unsigned)f2bf(p2) << 16);
    unsigned u3 = (unsigned)f2bf(v3) | ((unsigned)f2bf(p3) << 16);
    if (r < n)      h1s[(size_t)r * 32 + dw]        = u0;
    if (r + 4 < n)  h1s[(size_t)(r + 4) * 32 + dw]  = u1;
    if (r + 8 < n)  h1s[(size_t)(r + 8) * 32 + dw]  = u2;
    if (r + 12 < n) h1s[(size_t)(r + 12) * 32 + dw] = u3;
  }
}

// ---------------- fused layer-1 aggregate + bias + ReLU + GEMM2 -------------
// One wave/node; lane k = feature k; gathers read bf16x2 dword (k>>1).
// Gather indices min-clamped: loads always in-bounds even on bad records.
__global__ __launch_bounds__(BLK) void k_agg1f(const float* __restrict__ dinv,
                                               const int* __restrict__ rs,
                                               const int2* __restrict__ es,
                                               const unsigned* __restrict__ h1s,
                                               const float* __restrict__ b1,
                                               const float* __restrict__ W2,
                                               unsigned* __restrict__ h2s, int n, int E) {
  __shared__ float W2s[64 * 16];
  int tid = threadIdx.x;
  for (int i = tid; i < 1024; i += BLK) W2s[i] = W2[i];
  int v = blockIdx.x * 4 + (tid >> 6);
  int lane = tid & 63;
  int dw = lane >> 1, hb = lane & 1;
  unsigned nm1 = (unsigned)(n - 1);
  float acc = 0.f, di = 0.f;
  if (v < n) {
    int start = rs[v], end = rs[v + 1];
    start = max(0, min(start, E));
    end = max(start, min(end, E));
    di = dinv[v];
    acc = bfsel(h1s[(size_t)v * 32 + dw], hb);  // self (h1s already has dinv[v])
    int i = start;
    for (; i + 8 <= end; i += 8) {
      int2 e0 = es[i],     e1 = es[i + 1], e2 = es[i + 2], e3 = es[i + 3];
      int2 e4 = es[i + 4], e5 = es[i + 5], e6 = es[i + 6], e7 = es[i + 7];
      unsigned s0 = min((unsigned)e0.x, nm1), s1 = min((unsigned)e1.x, nm1);
      unsigned s2 = min((unsigned)e2.x, nm1), s3 = min((unsigned)e3.x, nm1);
      unsigned s4 = min((unsigned)e4.x, nm1), s5 = min((unsigned)e5.x, nm1);
      unsigned s6 = min((unsigned)e6.x, nm1), s7 = min((unsigned)e7.x, nm1);
      unsigned g0 = h1s[(size_t)s0 * 32 + dw];
      unsigned g1 = h1s[(size_t)s1 * 32 + dw];
      unsigned g2 = h1s[(size_t)s2 * 32 + dw];
      unsigned g3 = h1s[(size_t)s3 * 32 + dw];
      unsigned g4 = h1s[(size_t)s4 * 32 + dw];
      unsigned g5 = h1s[(size_t)s5 * 32 + dw];
      unsigned g6 = h1s[(size_t)s6 * 32 + dw];
      unsigned g7 = h1s[(size_t)s7 * 32 + dw];
      acc += __int_as_float(e0.y) * bfsel(g0, hb);
      acc += __int_as_float(e1.y) * bfsel(g1, hb);
      acc += __int_as_float(e2.y) * bfsel(g2, hb);
      acc += __int_as_float(e3.y) * bfsel(g3, hb);
      acc += __int_as_float(e4.y) * bfsel(g4, hb);
      acc += __int_as_float(e5.y) * bfsel(g5, hb);
      acc += __int_as_float(e6.y) * bfsel(g6, hb);
      acc += __int_as_float(e7.y) * bfsel(g7, hb);
    }
    for (; i < end; i++) {
      int2 e = es[i];
      unsigned sx = min((unsigned)e.x, nm1);
      acc += __int_as_float(e.y) * bfsel(h1s[(size_t)sx * 32 + dw], hb);
    }
  }
  float r = fmaxf(di * acc + b1[lane], 0.f);
  __syncthreads();  // W2s ready (all threads reach: no early returns above)
  int q = lane >> 4, c = lane & 15;
  float p = 0.f;
#pragma unroll
  for (int j = 0; j < 16; j++) {
    float rv = __shfl(r, 16 * q + j, 64);
    p += rv * W2s[(16 * q + j) * 16 + c];
  }
  p += __shfl_xor(p, 16, 64);
  p += __shfl_xor(p, 32, 64);
  p *= di;  // store h2s = dinv[v] * h2[v]
  float pp = __shfl_xor(p, 1, 64);
  if (v < n && lane < 16 && (lane & 1) == 0)
    h2s[(size_t)v * 8 + (lane >> 1)] = (unsigned)f2bf(p) | ((unsigned)f2bf(pp) << 16);
}

// ---------------- fused layer-2 aggregate + bias + log_softmax --------------
__global__ __launch_bounds__(BLK) void k_agg2f(const float* __restrict__ dinv,
                                               const int* __restrict__ rs,
                                               const int2* __restrict__ es,
                                               const unsigned* __restrict__ h2s,
                                               const float* __restrict__ b2,
                                               float* __restrict__ out, int n, int E) {
  int tid = threadIdx.x;
  int v = blockIdx.x * 16 + (tid >> 4);
  int j = tid & 15;
  if (v >= n) return;
  int dw = j >> 1, hb = j & 1;
  unsigned nm1 = (unsigned)(n - 1);
  int start = rs[v], end = rs[v + 1];
  start = max(0, min(start, E));
  end = max(start, min(end, E));
  float di = dinv[v];
  float acc = bfsel(h2s[(size_t)v * 8 + dw], hb);
  int i = start;
  for (; i + 4 <= end; i += 4) {
    int2 e0 = es[i], e1 = es[i + 1], e2 = es[i + 2], e3 = es[i + 3];
    unsigned s0 = min((unsigned)e0.x, nm1), s1 = min((unsigned)e1.x, nm1);
    unsigned s2 = min((unsigned)e2.x, nm1), s3 = min((unsigned)e3.x, nm1);
    unsigned g0 = h2s[(size_t)s0 * 8 + dw];
    unsigned g1 = h2s[(size_t)s1 * 8 + dw];
    unsigned g2 = h2s[(size_t)s2 * 8 + dw];
    unsigned g3 = h2s[(size_t)s3 * 8 + dw];
    acc += __int_as_float(e0.y) * bfsel(g0, hb);
    acc += __int_as_float(e1.y) * bfsel(g1, hb);
    acc += __int_as_float(e2.y) * bfsel(g2, hb);
    acc += __int_as_float(e3.y) * bfsel(g3, hb);
  }
  for (; i < end; i++) {
    int2 e = es[i];
    unsigned sx = min((unsigned)e.x, nm1);
    acc += __int_as_float(e.y) * bfsel(h2s[(size_t)sx * 8 + dw], hb);
  }
  acc = di * acc + b2[j];
  float m = acc;
  m = fmaxf(m, __shfl_xor(m, 1, 64));
  m = fmaxf(m, __shfl_xor(m, 2, 64));
  m = fmaxf(m, __shfl_xor(m, 4, 64));
  m = fmaxf(m, __shfl_xor(m, 8, 64));
  float ex = expf(acc - m);
  float s = ex;
  s += __shfl_xor(s, 1, 64);
  s += __shfl_xor(s, 2, 64);
  s += __shfl_xor(s, 4, 64);
  s += __shfl_xor(s, 8, 64);
  out[(size_t)v * 16 + j] = acc - m - logf(s);
}

extern "C" void kernel_launch(void* const* d_in, const int* in_sizes, int n_in,
                              void* d_out, int out_size, void* d_ws, size_t ws_size,
                              hipStream_t stream) {
  const float* x  = (const float*)d_in[0];
  const int*   ei = (const int*)d_in[1];   // int32 [2,E]
  const float* ew = (const float*)d_in[2];
  const float* W1 = (const float*)d_in[3];
  const float* b1 = (const float*)d_in[4];
  const float* W2 = (const float*)d_in[5];
  const float* b2 = (const float*)d_in[6];
  float* out = (float*)d_out;

  int n = in_sizes[0] / 128;
  int E = in_sizes[2];
  const int* src = ei;
  const int* dst = ei + E;

  // workspace layout (4B units), NO aliasing, es 8-byte aligned:
  // dinv[n] | cnt[n] | rs[n+1] | cur[n] | bs[256] | pad | es[2E] | h1s[32n] | h2s[8n]
  float*    ws   = (float*)d_ws;
  float*    dinv = ws;                           // n
  int*      cnt  = (int*)(dinv + n);             // n
  int*      rs   = cnt + n;                      // n+1
  int*      cur  = rs + n + 1;                   // n
  int*      bs   = cur + n;                      // 256
  uintptr_t ep   = ((uintptr_t)(bs + 256) + 7) & ~(uintptr_t)7;
  int2*     es   = (int2*)ep;                    // E records (2E ints), 8B aligned
  unsigned* h1s  = (unsigned*)(es + (size_t)E);  // 32n (bf16x2, 64 feats)
  unsigned* h2s  = h1s + 32 * (size_t)n;         // 8n  (bf16x2, 16 feats)

  int gN = (n + BLK - 1) / BLK;
  int gE = (E + BLK - 1) / BLK;
  int NB = (n + SC_CHUNK - 1) / SC_CHUNK;        // 49 for n=100k (must be <= 256)

  k_init<<<gN, BLK, 0, stream>>>(cnt, n);
  k_hist<<<gE, BLK, 0, stream>>>(dst, cnt, n, E);
  k_scan1<<<NB, BLK, 0, stream>>>(cnt, bs, n);
  k_scan2<<<1, BLK, 0, stream>>>(bs, NB);
  k_scan3<<<NB, BLK, 0, stream>>>(cnt, bs, rs, n, E);
  k_cur<<<gN, BLK, 0, stream>>>(rs, cur, n);
  k_scatter<<<gE, BLK, 0, stream>>>(src, dst, ew, cur, es, n, E);
  k_degdinv<<<(n + 15) / 16, BLK, 0, stream>>>(rs, es, dinv, n, E);

  k_gemm1<<<(n + 15) / 16, BLK, 0, stream>>>(x, W1, dinv, h1s, n);
  k_agg1f<<<(n + 3) / 4, BLK, 0, stream>>>(dinv, rs, es, h1s, b1, W2, h2s, n, E);
  k_agg2f<<<(n + 15) / 16, BLK, 0, stream>>>(dinv, rs, es, h2s, b2, out, n, E);
}

// Round 7
// 399.959 us; speedup vs baseline: 1.7668x; 1.1434x over previous
//
#include <hip/hip_runtime.h>
#include <cstdint>

#define BLK 256
#define EJ 16
#define CHUNK (BLK * EJ)   // 4096 edges per bucket/hist block
#define SLB 11             // slice = 2048 nodes
#define SLN 2048

__device__ inline unsigned short f2bf(float f) {  // RNE
  unsigned u = __float_as_uint(f);
  return (unsigned short)((u + 0x7FFF + ((u >> 16) & 1)) >> 16);
}
__device__ inline float bfsel(unsigned u, int hb) {  // decode half hb of bf16x2
  return __uint_as_float(hb ? (u & 0xFFFF0000u) : (u << 16));
}

// ---------------- zero the coarse histogram ----------------
__global__ __launch_bounds__(BLK) void k_zeroS(int* __restrict__ gcnt, int cap) {
  for (int i = threadIdx.x; i < cap; i += BLK) gcnt[i] = 0;
}

// ---------------- coarse histogram: 49 slices, LDS-private ----------------
__global__ __launch_bounds__(BLK) void k_hist49(const int* __restrict__ dst,
                                                int* __restrict__ gcnt,
                                                int n, int E, int NS) {
  __shared__ int c[64];
  int tid = threadIdx.x;
  if (tid < 64) c[tid] = 0;
  __syncthreads();
  int base = blockIdx.x * CHUNK;
#pragma unroll
  for (int j = 0; j < EJ; j++) {
    int idx = base + j * BLK + tid;
    if (idx < E) {
      int d = dst[idx];
      if ((unsigned)d < (unsigned)n) atomicAdd(&c[d >> SLB], 1);
    }
  }
  __syncthreads();
  if (tid < NS && c[tid]) atomicAdd(&gcnt[tid], c[tid]);
}

// ---------------- scan coarse counts -> segment starts (out of place) -------
__global__ __launch_bounds__(BLK) void k_scanS(const int* __restrict__ gcnt,
                                               int* __restrict__ segStart, int NS) {
  __shared__ int sd[BLK];
  int tid = threadIdx.x;
  int t = (tid < NS) ? gcnt[tid] : 0;
  sd[tid] = t;
  __syncthreads();
  int run = t;
  for (int off = 1; off < BLK; off <<= 1) {
    int u = (tid >= off) ? sd[tid - off] : 0;
    __syncthreads();
    run += u;
    sd[tid] = run;
    __syncthreads();
  }
  if (tid < NS) segStart[tid] = run - t;  // exclusive
  if (tid == 0) segStart[NS] = sd[BLK - 1];  // grand total (== E for valid input)
}

__global__ __launch_bounds__(BLK) void k_copyS(const int* __restrict__ segStart,
                                               int* __restrict__ segCur, int NS) {
  int tid = threadIdx.x;
  if (tid < NS) segCur[tid] = segStart[tid];
}

// ---------------- bucket edges into coarse slice segments ----------------
__global__ __launch_bounds__(BLK) void k_bucket(const int* __restrict__ src,
                                                const int* __restrict__ dst,
                                                const float* __restrict__ ew,
                                                int* __restrict__ segCur,
                                                int* __restrict__ bsrc,
                                                int* __restrict__ bdst,
                                                float* __restrict__ bew,
                                                int n, int E, int NS) {
  __shared__ int c[64], b[64], o[64];
  int tid = threadIdx.x;
  if (tid < 64) { c[tid] = 0; o[tid] = 0; }
  __syncthreads();
  int base = blockIdx.x * CHUNK;
  int dloc[EJ];
#pragma unroll
  for (int j = 0; j < EJ; j++) {
    int idx = base + j * BLK + tid;
    int d = -1;
    if (idx < E) {
      d = dst[idx];
      if ((unsigned)d >= (unsigned)n) d = -1;
    }
    dloc[j] = d;
    if (d >= 0) atomicAdd(&c[d >> SLB], 1);
  }
  __syncthreads();
  if (tid < NS && c[tid]) b[tid] = atomicAdd(&segCur[tid], c[tid]);
  __syncthreads();
#pragma unroll
  for (int j = 0; j < EJ; j++) {
    int idx = base + j * BLK + tid;
    int d = dloc[j];
    if (d >= 0) {
      int s = d >> SLB;
      int p = b[s] + atomicAdd(&o[s], 1);
      p = min(max(p, 0), E - 1);  // clamp safety
      bsrc[p] = src[idx];
      bdst[p] = d;
      bew[p] = ew[idx];
    }
  }
}

// ---------------- per-slice counting sort (all LDS) + rs + es + dinv --------
__global__ __launch_bounds__(BLK) void k_slice(const int* __restrict__ bsrc,
                                               const int* __restrict__ bdst,
                                               const float* __restrict__ bew,
                                               const int* __restrict__ segStart,
                                               int2* __restrict__ es,
                                               int* __restrict__ rs,
                                               float* __restrict__ dinv,
                                               int n, int E, int NS) {
  __shared__ int h[SLN];
  __shared__ int cu[SLN];
  __shared__ float wsum[SLN];
  __shared__ int sd[BLK];
  int s = blockIdx.x, tid = threadIdx.x;
  int node0 = s << SLB;
  int node1 = min(node0 + SLN, n);
  int sn = node1 - node0;
  int e0 = segStart[s], e1 = segStart[s + 1];
  e0 = max(0, min(e0, E));
  e1 = max(e0, min(e1, E));
  for (int i = tid; i < SLN; i += BLK) { h[i] = 0; wsum[i] = 0.f; }
  __syncthreads();
  for (int e = e0 + tid; e < e1; e += BLK) atomicAdd(&h[bdst[e] & (SLN - 1)], 1);
  __syncthreads();
  // exclusive scan of h -> cu, 8 bins/thread
  int bbase = tid * 8;
  int loc[8];
  int t = 0;
#pragma unroll
  for (int j = 0; j < 8; j++) { loc[j] = h[bbase + j]; t += loc[j]; }
  sd[tid] = t;
  __syncthreads();
  int run = t;
  for (int off = 1; off < BLK; off <<= 1) {
    int u = (tid >= off) ? sd[tid - off] : 0;
    __syncthreads();
    run += u;
    sd[tid] = run;
    __syncthreads();
  }
  int excl = run - t;
#pragma unroll
  for (int j = 0; j < 8; j++) {
    int bin = bbase + j;
    cu[bin] = excl;
    if (bin < sn) rs[node0 + bin] = e0 + excl;
    excl += loc[j];
  }
  if (s == NS - 1 && tid == 0) rs[n] = E;
  __syncthreads();
  // scatter into final CSR order + weighted-degree accumulation
  for (int e = e0 + tid; e < e1; e += BLK) {
    int d = bdst[e] & (SLN - 1);
    float w = bew[e];
    int sv = bsrc[e];
    int p = e0 + atomicAdd(&cu[d], 1);
    p = min(max(p, 0), E - 1);
    es[p] = make_int2(sv, __float_as_int(w));
    atomicAdd(&wsum[d], w);
  }
  __syncthreads();
  for (int l = tid; l < sn; l += BLK) {
    float deg = 1.0f + wsum[l];
    dinv[node0 + l] = deg > 0.f ? rsqrtf(deg) : 0.f;
  }
}

// ---------------- GEMM1: h1s[n,64](bf16x2) = dinv * (x[n,128] @ W1[128,64]) --
__global__ __launch_bounds__(BLK) void k_gemm1(const float* __restrict__ x,
                                               const float* __restrict__ W,
                                               const float* __restrict__ dinv,
                                               unsigned* __restrict__ h1s, int n) {
  __shared__ float Ws[128 * 64];
  __shared__ float xs[16][128];
  int tid = threadIdx.x;
  const float4* W4 = (const float4*)W;
  float4* Ws4 = (float4*)Ws;
#pragma unroll
  for (int i = 0; i < 8; i++) Ws4[tid + i * BLK] = W4[tid + i * BLK];
  int row0 = blockIdx.x * 16;
  int nrows = min(16, n - row0);
  const float4* x4 = (const float4*)(x + (size_t)row0 * 128);
  float4* xs4 = (float4*)xs;
  for (int i = tid; i < nrows * 32; i += BLK) xs4[i] = x4[i];
  __syncthreads();
  int col = tid & 63, rg = tid >> 6;  // wave-uniform rg -> xs reads broadcast
  float acc0 = 0.f, acc1 = 0.f, acc2 = 0.f, acc3 = 0.f;
#pragma unroll 4
  for (int k = 0; k < 128; k++) {
    float w = Ws[k * 64 + col];
    acc0 += xs[rg][k] * w;
    acc1 += xs[rg + 4][k] * w;
    acc2 += xs[rg + 8][k] * w;
    acc3 += xs[rg + 12][k] * w;
  }
  // scale by dinv[row], pack bf16x2 (even col packs {col, col+1})
  int r = row0 + rg;
  int rc0 = min(r, n - 1), rc1 = min(r + 4, n - 1),
      rc2 = min(r + 8, n - 1), rc3 = min(r + 12, n - 1);
  float v0 = acc0 * dinv[rc0], v1 = acc1 * dinv[rc1],
        v2 = acc2 * dinv[rc2], v3 = acc3 * dinv[rc3];
  float p0 = __shfl_xor(v0, 1, 64), p1 = __shfl_xor(v1, 1, 64),
        p2 = __shfl_xor(v2, 1, 64), p3 = __shfl_xor(v3, 1, 64);
  if ((col & 1) == 0) {
    int dw = col >> 1;
    unsigned u0 = (unsigned)f2bf(v0) | ((unsigned)f2bf(p0) << 16);
    unsigned u1 = (unsigned)f2bf(v1) | ((unsigned)f2bf(p1) << 16);
    unsigned u2 = (unsigned)f2bf(v2) | ((unsigned)f2bf(p2) << 16);
    unsigned u3 = (unsigned)f2bf(v3) | ((unsigned)f2bf(p3) << 16);
    if (r < n)      h1s[(size_t)r * 32 + dw]        = u0;
    if (r + 4 < n)  h1s[(size_t)(r + 4) * 32 + dw]  = u1;
    if (r + 8 < n)  h1s[(size_t)(r + 8) * 32 + dw]  = u2;
    if (r + 12 < n) h1s[(size_t)(r + 12) * 32 + dw] = u3;
  }
}

// ---------------- fused layer-1 aggregate + bias + ReLU + GEMM2 -------------
__global__ __launch_bounds__(BLK) void k_agg1f(const float* __restrict__ dinv,
                                               const int* __restrict__ rs,
                                               const int2* __restrict__ es,
                                               const unsigned* __restrict__ h1s,
                                               const float* __restrict__ b1,
                                               const float* __restrict__ W2,
                                               unsigned* __restrict__ h2s, int n, int E) {
  __shared__ float W2s[64 * 16];
  int tid = threadIdx.x;
  for (int i = tid; i < 1024; i += BLK) W2s[i] = W2[i];
  int v = blockIdx.x * 4 + (tid >> 6);
  int lane = tid & 63;
  int dw = lane >> 1, hb = lane & 1;
  unsigned nm1 = (unsigned)(n - 1);
  float acc = 0.f, di = 0.f;
  if (v < n) {
    int start = rs[v], end = rs[v + 1];
    start = max(0, min(start, E));
    end = max(start, min(end, E));
    di = dinv[v];
    acc = bfsel(h1s[(size_t)v * 32 + dw], hb);  // self (h1s already has dinv[v])
    int i = start;
    for (; i + 8 <= end; i += 8) {
      int2 e0 = es[i],     e1 = es[i + 1], e2 = es[i + 2], e3 = es[i + 3];
      int2 e4 = es[i + 4], e5 = es[i + 5], e6 = es[i + 6], e7 = es[i + 7];
      unsigned s0 = min((unsigned)e0.x, nm1), s1 = min((unsigned)e1.x, nm1);
      unsigned s2 = min((unsigned)e2.x, nm1), s3 = min((unsigned)e3.x, nm1);
      unsigned s4 = min((unsigned)e4.x, nm1), s5 = min((unsigned)e5.x, nm1);
      unsigned s6 = min((unsigned)e6.x, nm1), s7 = min((unsigned)e7.x, nm1);
      unsigned g0 = h1s[(size_t)s0 * 32 + dw];
      unsigned g1 = h1s[(size_t)s1 * 32 + dw];
      unsigned g2 = h1s[(size_t)s2 * 32 + dw];
      unsigned g3 = h1s[(size_t)s3 * 32 + dw];
      unsigned g4 = h1s[(size_t)s4 * 32 + dw];
      unsigned g5 = h1s[(size_t)s5 * 32 + dw];
      unsigned g6 = h1s[(size_t)s6 * 32 + dw];
      unsigned g7 = h1s[(size_t)s7 * 32 + dw];
      acc += __int_as_float(e0.y) * bfsel(g0, hb);
      acc += __int_as_float(e1.y) * bfsel(g1, hb);
      acc += __int_as_float(e2.y) * bfsel(g2, hb);
      acc += __int_as_float(e3.y) * bfsel(g3, hb);
      acc += __int_as_float(e4.y) * bfsel(g4, hb);
      acc += __int_as_float(e5.y) * bfsel(g5, hb);
      acc += __int_as_float(e6.y) * bfsel(g6, hb);
      acc += __int_as_float(e7.y) * bfsel(g7, hb);
    }
    for (; i < end; i++) {
      int2 e = es[i];
      unsigned sx = min((unsigned)e.x, nm1);
      acc += __int_as_float(e.y) * bfsel(h1s[(size_t)sx * 32 + dw], hb);
    }
  }
  float r = fmaxf(di * acc + b1[lane], 0.f);
  __syncthreads();  // W2s ready (all threads reach: no early returns above)
  int q = lane >> 4, c = lane & 15;
  float p = 0.f;
#pragma unroll
  for (int j = 0; j < 16; j++) {
    float rv = __shfl(r, 16 * q + j, 64);
    p += rv * W2s[(16 * q + j) * 16 + c];
  }
  p += __shfl_xor(p, 16, 64);
  p += __shfl_xor(p, 32, 64);
  p *= di;  // store h2s = dinv[v] * h2[v]
  float pp = __shfl_xor(p, 1, 64);
  if (v < n && lane < 16 && (lane & 1) == 0)
    h2s[(size_t)v * 8 + (lane >> 1)] = (unsigned)f2bf(p) | ((unsigned)f2bf(pp) << 16);
}

// ---------------- fused layer-2 aggregate + bias + log_softmax --------------
__global__ __launch_bounds__(BLK) void k_agg2f(const float* __restrict__ dinv,
                                               const int* __restrict__ rs,
                                               const int2* __restrict__ es,
                                               const unsigned* __restrict__ h2s,
                                               const float* __restrict__ b2,
                                               float* __restrict__ out, int n, int E) {
  int tid = threadIdx.x;
  int v = blockIdx.x * 16 + (tid >> 4);
  int j = tid & 15;
  if (v >= n) return;
  int dw = j >> 1, hb = j & 1;
  unsigned nm1 = (unsigned)(n - 1);
  int start = rs[v], end = rs[v + 1];
  start = max(0, min(start, E));
  end = max(start, min(end, E));
  float di = dinv[v];
  float acc = bfsel(h2s[(size_t)v * 8 + dw], hb);
  int i = start;
  for (; i + 4 <= end; i += 4) {
    int2 e0 = es[i], e1 = es[i + 1], e2 = es[i + 2], e3 = es[i + 3];
    unsigned s0 = min((unsigned)e0.x, nm1), s1 = min((unsigned)e1.x, nm1);
    unsigned s2 = min((unsigned)e2.x, nm1), s3 = min((unsigned)e3.x, nm1);
    unsigned g0 = h2s[(size_t)s0 * 8 + dw];
    unsigned g1 = h2s[(size_t)s1 * 8 + dw];
    unsigned g2 = h2s[(size_t)s2 * 8 + dw];
    unsigned g3 = h2s[(size_t)s3 * 8 + dw];
    acc += __int_as_float(e0.y) * bfsel(g0, hb);
    acc += __int_as_float(e1.y) * bfsel(g1, hb);
    acc += __int_as_float(e2.y) * bfsel(g2, hb);
    acc += __int_as_float(e3.y) * bfsel(g3, hb);
  }
  for (; i < end; i++) {
    int2 e = es[i];
    unsigned sx = min((unsigned)e.x, nm1);
    acc += __int_as_float(e.y) * bfsel(h2s[(size_t)sx * 8 + dw], hb);
  }
  acc = di * acc + b2[j];
  float m = acc;
  m = fmaxf(m, __shfl_xor(m, 1, 64));
  m = fmaxf(m, __shfl_xor(m, 2, 64));
  m = fmaxf(m, __shfl_xor(m, 4, 64));
  m = fmaxf(m, __shfl_xor(m, 8, 64));
  float ex = expf(acc - m);
  float s = ex;
  s += __shfl_xor(s, 1, 64);
  s += __shfl_xor(s, 2, 64);
  s += __shfl_xor(s, 4, 64);
  s += __shfl_xor(s, 8, 64);
  out[(size_t)v * 16 + j] = acc - m - logf(s);
}

extern "C" void kernel_launch(void* const* d_in, const int* in_sizes, int n_in,
                              void* d_out, int out_size, void* d_ws, size_t ws_size,
                              hipStream_t stream) {
  const float* x  = (const float*)d_in[0];
  const int*   ei = (const int*)d_in[1];   // int32 [2,E]
  const float* ew = (const float*)d_in[2];
  const float* W1 = (const float*)d_in[3];
  const float* b1 = (const float*)d_in[4];
  const float* W2 = (const float*)d_in[5];
  const float* b2 = (const float*)d_in[6];
  float* out = (float*)d_out;

  int n = in_sizes[0] / 128;
  int E = in_sizes[2];
  const int* src = ei;
  const int* dst = ei + E;

  int NS = ((n - 1) >> SLB) + 1;  // 49 for n=100k
  if (NS > 255) NS = 255;         // safety (would need bigger slices; n=100k fine)
  const int NSCAP = 260;

  // workspace: all arrays at 16B-aligned offsets (R5 lesson: int2 alignment!)
  char* wp = (char*)d_ws;
  auto alloc = [&](size_t bytes) -> char* {
    char* r = wp;
    wp += (bytes + 15) & ~(size_t)15;
    return r;
  };
  int*      gcnt     = (int*)alloc((size_t)NSCAP * 4);
  int*      segStart = (int*)alloc((size_t)(NSCAP + 1) * 4);
  int*      segCur   = (int*)alloc((size_t)NSCAP * 4);
  int*      bsrc     = (int*)alloc((size_t)E * 4);
  int*      bdst     = (int*)alloc((size_t)E * 4);
  float*    bew      = (float*)alloc((size_t)E * 4);
  int2*     es       = (int2*)alloc((size_t)E * 8);
  int*      rs       = (int*)alloc((size_t)(n + 1) * 4);
  float*    dinv     = (float*)alloc((size_t)n * 4);
  unsigned* h1s      = (unsigned*)alloc((size_t)n * 32 * 4);
  unsigned* h2s      = (unsigned*)alloc((size_t)n * 8 * 4);

  int gC = (E + CHUNK - 1) / CHUNK;  // 391 for E=1.6M

  k_zeroS<<<1, BLK, 0, stream>>>(gcnt, NSCAP);
  k_hist49<<<gC, BLK, 0, stream>>>(dst, gcnt, n, E, NS);
  k_scanS<<<1, BLK, 0, stream>>>(gcnt, segStart, NS);
  k_copyS<<<1, BLK, 0, stream>>>(segStart, segCur, NS);
  k_bucket<<<gC, BLK, 0, stream>>>(src, dst, ew, segCur, bsrc, bdst, bew, n, E, NS);
  k_slice<<<NS, BLK, 0, stream>>>(bsrc, bdst, bew, segStart, es, rs, dinv, n, E, NS);

  k_gemm1<<<(n + 15) / 16, BLK, 0, stream>>>(x, W1, dinv, h1s, n);
  k_agg1f<<<(n + 3) / 4, BLK, 0, stream>>>(dinv, rs, es, h1s, b1, W2, h2s, n, E);
  k_agg2f<<<(n + 15) / 16, BLK, 0, stream>>>(dinv, rs, es, h2s, b2, out, n, E);
}

// Round 8
// 388.965 us; speedup vs baseline: 1.8168x; 1.0283x over previous
//
#include <hip/hip_runtime.h>
#include <cstdint>

#define BLK 256
#define EJ 16
#define CHUNK (BLK * EJ)   // 4096 edges per bucket/hist block
#define SLB 11             // slice = 2048 nodes
#define SLN 2048

__device__ inline unsigned short f2bf(float f) {  // RNE
  unsigned u = __float_as_uint(f);
  return (unsigned short)((u + 0x7FFF + ((u >> 16) & 1)) >> 16);
}
__device__ inline float bflo(unsigned u) { return __uint_as_float(u << 16); }
__device__ inline float bfhi(unsigned u) { return __uint_as_float(u & 0xFFFF0000u); }

// ---------------- zero the coarse histogram ----------------
__global__ __launch_bounds__(BLK) void k_zeroS(int* __restrict__ gcnt, int cap) {
  for (int i = threadIdx.x; i < cap; i += BLK) gcnt[i] = 0;
}

// ---------------- coarse histogram: 49 slices, LDS-private ----------------
__global__ __launch_bounds__(BLK) void k_hist49(const int* __restrict__ dst,
                                                int* __restrict__ gcnt,
                                                int n, int E, int NS) {
  __shared__ int c[64];
  int tid = threadIdx.x;
  if (tid < 64) c[tid] = 0;
  __syncthreads();
  int base = blockIdx.x * CHUNK;
#pragma unroll
  for (int j = 0; j < EJ; j++) {
    int idx = base + j * BLK + tid;
    if (idx < E) {
      int d = dst[idx];
      if ((unsigned)d < (unsigned)n) atomicAdd(&c[d >> SLB], 1);
    }
  }
  __syncthreads();
  if (tid < NS && c[tid]) atomicAdd(&gcnt[tid], c[tid]);
}

// ---------------- scan coarse counts -> segment starts (out of place) -------
__global__ __launch_bounds__(BLK) void k_scanS(const int* __restrict__ gcnt,
                                               int* __restrict__ segStart, int NS) {
  __shared__ int sd[BLK];
  int tid = threadIdx.x;
  int t = (tid < NS) ? gcnt[tid] : 0;
  sd[tid] = t;
  __syncthreads();
  int run = t;
  for (int off = 1; off < BLK; off <<= 1) {
    int u = (tid >= off) ? sd[tid - off] : 0;
    __syncthreads();
    run += u;
    sd[tid] = run;
    __syncthreads();
  }
  if (tid < NS) segStart[tid] = run - t;  // exclusive
  if (tid == 0) segStart[NS] = sd[BLK - 1];  // grand total
}

__global__ __launch_bounds__(BLK) void k_copyS(const int* __restrict__ segStart,
                                               int* __restrict__ segCur, int NS) {
  int tid = threadIdx.x;
  if (tid < NS) segCur[tid] = segStart[tid];
}

// ---------------- bucket edges into coarse slice segments (packed int2) -----
// bpk[p] = { (dstLocal<<20) | src, ew }   (requires n <= 2^20)
__global__ __launch_bounds__(BLK) void k_bucket(const int* __restrict__ src,
                                                const int* __restrict__ dst,
                                                const float* __restrict__ ew,
                                                int* __restrict__ segCur,
                                                int2* __restrict__ bpk,
                                                int n, int E, int NS) {
  __shared__ int c[64], b[64], o[64];
  int tid = threadIdx.x;
  if (tid < 64) { c[tid] = 0; o[tid] = 0; }
  __syncthreads();
  int base = blockIdx.x * CHUNK;
  int dloc[EJ];
#pragma unroll
  for (int j = 0; j < EJ; j++) {
    int idx = base + j * BLK + tid;
    int d = -1;
    if (idx < E) {
      d = dst[idx];
      if ((unsigned)d >= (unsigned)n) d = -1;
    }
    dloc[j] = d;
    if (d >= 0) atomicAdd(&c[d >> SLB], 1);
  }
  __syncthreads();
  if (tid < NS && c[tid]) b[tid] = atomicAdd(&segCur[tid], c[tid]);
  __syncthreads();
#pragma unroll
  for (int j = 0; j < EJ; j++) {
    int idx = base + j * BLK + tid;
    int d = dloc[j];
    if (d >= 0) {
      int s = d >> SLB;
      int p = b[s] + atomicAdd(&o[s], 1);
      p = min(max(p, 0), E - 1);  // clamp safety
      int packed = ((d & (SLN - 1)) << 20) | (src[idx] & 0xFFFFF);
      bpk[p] = make_int2(packed, __float_as_int(ew[idx]));
    }
  }
}

// ---------------- per-slice counting sort (all LDS) + rs + es + dinv --------
__global__ __launch_bounds__(BLK) void k_slice(const int2* __restrict__ bpk,
                                               const int* __restrict__ segStart,
                                               int2* __restrict__ es,
                                               int* __restrict__ rs,
                                               float* __restrict__ dinv,
                                               int n, int E, int NS) {
  __shared__ int h[SLN];
  __shared__ int cu[SLN];
  __shared__ float wsum[SLN];
  __shared__ int sd[BLK];
  int s = blockIdx.x, tid = threadIdx.x;
  int node0 = s << SLB;
  int node1 = min(node0 + SLN, n);
  int sn = node1 - node0;
  int e0 = segStart[s], e1 = segStart[s + 1];
  e0 = max(0, min(e0, E));
  e1 = max(e0, min(e1, E));
  for (int i = tid; i < SLN; i += BLK) { h[i] = 0; wsum[i] = 0.f; }
  __syncthreads();
  for (int e = e0 + tid; e < e1; e += BLK)
    atomicAdd(&h[(unsigned)bpk[e].x >> 20], 1);
  __syncthreads();
  // exclusive scan of h -> cu, 8 bins/thread
  int bbase = tid * 8;
  int loc[8];
  int t = 0;
#pragma unroll
  for (int j = 0; j < 8; j++) { loc[j] = h[bbase + j]; t += loc[j]; }
  sd[tid] = t;
  __syncthreads();
  int run = t;
  for (int off = 1; off < BLK; off <<= 1) {
    int u = (tid >= off) ? sd[tid - off] : 0;
    __syncthreads();
    run += u;
    sd[tid] = run;
    __syncthreads();
  }
  int excl = run - t;
#pragma unroll
  for (int j = 0; j < 8; j++) {
    int bin = bbase + j;
    cu[bin] = excl;
    if (bin < sn) rs[node0 + bin] = e0 + excl;
    excl += loc[j];
  }
  if (s == NS - 1 && tid == 0) rs[n] = E;
  __syncthreads();
  // scatter into final CSR order + weighted-degree accumulation
  for (int e = e0 + tid; e < e1; e += BLK) {
    int2 pk = bpk[e];
    int dl = (unsigned)pk.x >> 20;
    int sv = pk.x & 0xFFFFF;
    float w = __int_as_float(pk.y);
    int p = e0 + atomicAdd(&cu[dl], 1);
    p = min(max(p, 0), E - 1);
    es[p] = make_int2(sv, pk.y);
    atomicAdd(&wsum[dl], w);
  }
  __syncthreads();
  for (int l = tid; l < sn; l += BLK) {
    float deg = 1.0f + wsum[l];
    dinv[node0 + l] = deg > 0.f ? rsqrtf(deg) : 0.f;
  }
}

// ---------------- GEMM1: h1s[n,64](bf16x2) = dinv * (x[n,128] @ W1[128,64]) --
__global__ __launch_bounds__(BLK) void k_gemm1(const float* __restrict__ x,
                                               const float* __restrict__ W,
                                               const float* __restrict__ dinv,
                                               unsigned* __restrict__ h1s, int n) {
  __shared__ float Ws[128 * 64];
  __shared__ float xs[16][128];
  int tid = threadIdx.x;
  const float4* W4 = (const float4*)W;
  float4* Ws4 = (float4*)Ws;
#pragma unroll
  for (int i = 0; i < 8; i++) Ws4[tid + i * BLK] = W4[tid + i * BLK];
  int row0 = blockIdx.x * 16;
  int nrows = min(16, n - row0);
  const float4* x4 = (const float4*)(x + (size_t)row0 * 128);
  float4* xs4 = (float4*)xs;
  for (int i = tid; i < nrows * 32; i += BLK) xs4[i] = x4[i];
  __syncthreads();
  int col = tid & 63, rg = tid >> 6;  // wave-uniform rg -> xs reads broadcast
  float acc0 = 0.f, acc1 = 0.f, acc2 = 0.f, acc3 = 0.f;
#pragma unroll 4
  for (int k = 0; k < 128; k++) {
    float w = Ws[k * 64 + col];
    acc0 += xs[rg][k] * w;
    acc1 += xs[rg + 4][k] * w;
    acc2 += xs[rg + 8][k] * w;
    acc3 += xs[rg + 12][k] * w;
  }
  // scale by dinv[row], pack bf16x2 (even col packs {col, col+1})
  int r = row0 + rg;
  int rc0 = min(r, n - 1), rc1 = min(r + 4, n - 1),
      rc2 = min(r + 8, n - 1), rc3 = min(r + 12, n - 1);
  float v0 = acc0 * dinv[rc0], v1 = acc1 * dinv[rc1],
        v2 = acc2 * dinv[rc2], v3 = acc3 * dinv[rc3];
  float p0 = __shfl_xor(v0, 1, 64), p1 = __shfl_xor(v1, 1, 64),
        p2 = __shfl_xor(v2, 1, 64), p3 = __shfl_xor(v3, 1, 64);
  if ((col & 1) == 0) {
    int dw = col >> 1;
    unsigned u0 = (unsigned)f2bf(v0) | ((unsigned)f2bf(p0) << 16);
    unsigned u1 = (unsigned)f2bf(v1) | ((unsigned)f2bf(p1) << 16);
    unsigned u2 = (unsigned)f2bf(v2) | ((unsigned)f2bf(p2) << 16);
    unsigned u3 = (unsigned)f2bf(v3) | ((unsigned)f2bf(p3) << 16);
    if (r < n)      h1s[(size_t)r * 32 + dw]        = u0;
    if (r + 4 < n)  h1s[(size_t)(r + 4) * 32 + dw]  = u1;
    if (r + 8 < n)  h1s[(size_t)(r + 8) * 32 + dw]  = u2;
    if (r + 12 < n) h1s[(size_t)(r + 12) * 32 + dw] = u3;
  }
}

// ---------------- fused layer-1 aggregate + bias + ReLU + GEMM2 -------------
// One wave/node, dword-per-lane: lanes 0-31 = edge i, lanes 32-63 = edge i+1;
// lane owns features {2d, 2d+1} as float2. 16 edges per main iteration.
__global__ __launch_bounds__(BLK) void k_agg1f(const float* __restrict__ dinv,
                                               const int* __restrict__ rs,
                                               const int2* __restrict__ es,
                                               const unsigned* __restrict__ h1s,
                                               const float* __restrict__ b1,
                                               const float* __restrict__ W2,
                                               unsigned* __restrict__ h2s, int n, int E) {
  __shared__ float W2s[64 * 16];
  int tid = threadIdx.x;
  for (int i = tid; i < 1024; i += BLK) W2s[i] = W2[i];
  int v = blockIdx.x * 4 + (tid >> 6);
  int lane = tid & 63;
  int half = lane >> 5;   // which edge of the pair
  int d = lane & 31;      // dword -> features 2d, 2d+1
  unsigned nm1 = (unsigned)(n - 1);
  float ax = 0.f, ay = 0.f, di = 0.f;
  if (v < n) {
    int start = rs[v], end = rs[v + 1];
    start = max(0, min(start, E));
    end = max(start, min(end, E));
    di = dinv[v];
    if (half == 0) {
      unsigned us = h1s[(size_t)v * 32 + d];  // self (h1s already has dinv[v])
      ax = bflo(us); ay = bfhi(us);
    }
    int i = start;
    for (; i + 16 <= end; i += 16) {
      int2 e0 = es[i + 0 + half],  e1 = es[i + 2 + half];
      int2 e2 = es[i + 4 + half],  e3 = es[i + 6 + half];
      int2 e4 = es[i + 8 + half],  e5 = es[i + 10 + half];
      int2 e6 = es[i + 12 + half], e7 = es[i + 14 + half];
      unsigned g0 = h1s[(size_t)min((unsigned)e0.x, nm1) * 32 + d];
      unsigned g1 = h1s[(size_t)min((unsigned)e1.x, nm1) * 32 + d];
      unsigned g2 = h1s[(size_t)min((unsigned)e2.x, nm1) * 32 + d];
      unsigned g3 = h1s[(size_t)min((unsigned)e3.x, nm1) * 32 + d];
      unsigned g4 = h1s[(size_t)min((unsigned)e4.x, nm1) * 32 + d];
      unsigned g5 = h1s[(size_t)min((unsigned)e5.x, nm1) * 32 + d];
      unsigned g6 = h1s[(size_t)min((unsigned)e6.x, nm1) * 32 + d];
      unsigned g7 = h1s[(size_t)min((unsigned)e7.x, nm1) * 32 + d];
      float w0 = __int_as_float(e0.y), w1 = __int_as_float(e1.y);
      float w2 = __int_as_float(e2.y), w3 = __int_as_float(e3.y);
      float w4 = __int_as_float(e4.y), w5 = __int_as_float(e5.y);
      float w6 = __int_as_float(e6.y), w7 = __int_as_float(e7.y);
      ax += w0 * bflo(g0); ay += w0 * bfhi(g0);
      ax += w1 * bflo(g1); ay += w1 * bfhi(g1);
      ax += w2 * bflo(g2); ay += w2 * bfhi(g2);
      ax += w3 * bflo(g3); ay += w3 * bfhi(g3);
      ax += w4 * bflo(g4); ay += w4 * bfhi(g4);
      ax += w5 * bflo(g5); ay += w5 * bfhi(g5);
      ax += w6 * bflo(g6); ay += w6 * bfhi(g6);
      ax += w7 * bflo(g7); ay += w7 * bfhi(g7);
    }
    for (; i + 2 <= end; i += 2) {
      int2 e = es[i + half];
      unsigned g = h1s[(size_t)min((unsigned)e.x, nm1) * 32 + d];
      float w = __int_as_float(e.y);
      ax += w * bflo(g); ay += w * bfhi(g);
    }
    if (i < end && half == 0) {
      int2 e = es[i];
      unsigned g = h1s[(size_t)min((unsigned)e.x, nm1) * 32 + d];
      float w = __int_as_float(e.y);
      ax += w * bflo(g); ay += w * bfhi(g);
    }
  }
  // fold halves, redistribute to feature-per-lane layout
  ax += __shfl_xor(ax, 32, 64);
  ay += __shfl_xor(ay, 32, 64);
  float rx = __shfl(ax, lane >> 1, 64);
  float ry = __shfl(ay, lane >> 1, 64);
  float av = (lane & 1) ? ry : rx;
  float r = fmaxf(di * av + b1[lane], 0.f);
  __syncthreads();  // W2s ready (all threads reach: no early returns above)
  int q = lane >> 4, c = lane & 15;
  float p = 0.f;
#pragma unroll
  for (int j = 0; j < 16; j++) {
    float rv = __shfl(r, 16 * q + j, 64);
    p += rv * W2s[(16 * q + j) * 16 + c];
  }
  p += __shfl_xor(p, 16, 64);
  p += __shfl_xor(p, 32, 64);
  p *= di;  // store h2s = dinv[v] * h2[v]
  float pp = __shfl_xor(p, 1, 64);
  if (v < n && lane < 16 && (lane & 1) == 0)
    h2s[(size_t)v * 8 + (lane >> 1)] = (unsigned)f2bf(p) | ((unsigned)f2bf(pp) << 16);
}

// ---------------- fused layer-2 aggregate + bias + log_softmax --------------
// 16-lane group per node; two 8-lane subgroups process 2 edges at once.
__global__ __launch_bounds__(BLK) void k_agg2f(const float* __restrict__ dinv,
                                               const int* __restrict__ rs,
                                               const int2* __restrict__ es,
                                               const unsigned* __restrict__ h2s,
                                               const float* __restrict__ b2,
                                               float* __restrict__ out, int n, int E) {
  int tid = threadIdx.x;
  int v = blockIdx.x * 16 + (tid >> 4);
  int j = tid & 15;
  if (v >= n) return;
  int g8 = j >> 3, d = j & 7;  // subgroup / dword (features 2d, 2d+1)
  unsigned nm1 = (unsigned)(n - 1);
  int start = rs[v], end = rs[v + 1];
  start = max(0, min(start, E));
  end = max(start, min(end, E));
  float di = dinv[v];
  float ax = 0.f, ay = 0.f;
  if (g8 == 0) {
    unsigned us = h2s[(size_t)v * 8 + d];
    ax = bflo(us); ay = bfhi(us);
  }
  int i = start;
  for (; i + 8 <= end; i += 8) {
    int2 e0 = es[i + 0 + g8], e1 = es[i + 2 + g8];
    int2 e2 = es[i + 4 + g8], e3 = es[i + 6 + g8];
    unsigned g0 = h2s[(size_t)min((unsigned)e0.x, nm1) * 8 + d];
    unsigned g1 = h2s[(size_t)min((unsigned)e1.x, nm1) * 8 + d];
    unsigned g2 = h2s[(size_t)min((unsigned)e2.x, nm1) * 8 + d];
    unsigned g3 = h2s[(size_t)min((unsigned)e3.x, nm1) * 8 + d];
    float w0 = __int_as_float(e0.y), w1 = __int_as_float(e1.y);
    float w2 = __int_as_float(e2.y), w3 = __int_as_float(e3.y);
    ax += w0 * bflo(g0); ay += w0 * bfhi(g0);
    ax += w1 * bflo(g1); ay += w1 * bfhi(g1);
    ax += w2 * bflo(g2); ay += w2 * bfhi(g2);
    ax += w3 * bflo(g3); ay += w3 * bfhi(g3);
  }
  for (; i + 2 <= end; i += 2) {
    int2 e = es[i + g8];
    unsigned g = h2s[(size_t)min((unsigned)e.x, nm1) * 8 + d];
    float w = __int_as_float(e.y);
    ax += w * bflo(g); ay += w * bfhi(g);
  }
  if (i < end && g8 == 0) {
    int2 e = es[i];
    unsigned g = h2s[(size_t)min((unsigned)e.x, nm1) * 8 + d];
    float w = __int_as_float(e.y);
    ax += w * bflo(g); ay += w * bfhi(g);
  }
  // fold subgroups, redistribute to feature-per-lane within the 16-lane group
  ax += __shfl_xor(ax, 8, 64);
  ay += __shfl_xor(ay, 8, 64);
  int lane = tid & 63;
  int base = lane & ~15;
  float rx = __shfl(ax, base + (j >> 1), 64);
  float ry = __shfl(ay, base + (j >> 1), 64);
  float av = (j & 1) ? ry : rx;
  float acc = di * av + b2[j];
  float m = acc;
  m = fmaxf(m, __shfl_xor(m, 1, 64));
  m = fmaxf(m, __shfl_xor(m, 2, 64));
  m = fmaxf(m, __shfl_xor(m, 4, 64));
  m = fmaxf(m, __shfl_xor(m, 8, 64));
  float ex = expf(acc - m);
  float s = ex;
  s += __shfl_xor(s, 1, 64);
  s += __shfl_xor(s, 2, 64);
  s += __shfl_xor(s, 4, 64);
  s += __shfl_xor(s, 8, 64);
  out[(size_t)v * 16 + j] = acc - m - logf(s);
}

extern "C" void kernel_launch(void* const* d_in, const int* in_sizes, int n_in,
                              void* d_out, int out_size, void* d_ws, size_t ws_size,
                              hipStream_t stream) {
  const float* x  = (const float*)d_in[0];
  const int*   ei = (const int*)d_in[1];   // int32 [2,E]
  const float* ew = (const float*)d_in[2];
  const float* W1 = (const float*)d_in[3];
  const float* b1 = (const float*)d_in[4];
  const float* W2 = (const float*)d_in[5];
  const float* b2 = (const float*)d_in[6];
  float* out = (float*)d_out;

  int n = in_sizes[0] / 128;
  int E = in_sizes[2];
  const int* src = ei;
  const int* dst = ei + E;

  int NS = ((n - 1) >> SLB) + 1;  // 49 for n=100k
  if (NS > 255) NS = 255;         // safety (n=100k fine)
  const int NSCAP = 260;

  // workspace: all arrays at 16B-aligned offsets (R5 lesson: int2 alignment!)
  char* wp = (char*)d_ws;
  auto alloc = [&](size_t bytes) -> char* {
    char* r = wp;
    wp += (bytes + 15) & ~(size_t)15;
    return r;
  };
  int*      gcnt     = (int*)alloc((size_t)NSCAP * 4);
  int*      segStart = (int*)alloc((size_t)(NSCAP + 1) * 4);
  int*      segCur   = (int*)alloc((size_t)NSCAP * 4);
  int2*     bpk      = (int2*)alloc((size_t)E * 8);
  int2*     es       = (int2*)alloc((size_t)E * 8);
  int*      rs       = (int*)alloc((size_t)(n + 1) * 4);
  float*    dinv     = (float*)alloc((size_t)n * 4);
  unsigned* h1s      = (unsigned*)alloc((size_t)n * 32 * 4);
  unsigned* h2s      = (unsigned*)alloc((size_t)n * 8 * 4);

  int gC = (E + CHUNK - 1) / CHUNK;  // 391 for E=1.6M

  k_zeroS<<<1, BLK, 0, stream>>>(gcnt, NSCAP);
  k_hist49<<<gC, BLK, 0, stream>>>(dst, gcnt, n, E, NS);
  k_scanS<<<1, BLK, 0, stream>>>(gcnt, segStart, NS);
  k_copyS<<<1, BLK, 0, stream>>>(segStart, segCur, NS);
  k_bucket<<<gC, BLK, 0, stream>>>(src, dst, ew, segCur, bpk, n, E, NS);
  k_slice<<<NS, BLK, 0, stream>>>(bpk, segStart, es, rs, dinv, n, E, NS);

  k_gemm1<<<(n + 15) / 16, BLK, 0, stream>>>(x, W1, dinv, h1s, n);
  k_agg1f<<<(n + 3) / 4, BLK, 0, stream>>>(dinv, rs, es, h1s, b1, W2, h2s, n, E);
  k_agg2f<<<(n + 15) / 16, BLK, 0, stream>>>(dinv, rs, es, h2s, b2, out, n, E);
}

// Round 9
// 296.375 us; speedup vs baseline: 2.3843x; 1.3124x over previous
//
#include <hip/hip_runtime.h>
#include <cstdint>

#define BLK 256
#define EJ 16
#define CHUNK (BLK * EJ)   // 4096 edges per bucket/hist block
#define SLB 9              // slice = 512 nodes
#define SLN 512

__device__ inline unsigned short f2bf(float f) {  // RNE
  unsigned u = __float_as_uint(f);
  return (unsigned short)((u + 0x7FFF + ((u >> 16) & 1)) >> 16);
}
__device__ inline float bflo(unsigned u) { return __uint_as_float(u << 16); }
__device__ inline float bfhi(unsigned u) { return __uint_as_float(u & 0xFFFF0000u); }

// ---------------- zero the coarse histogram ----------------
__global__ __launch_bounds__(BLK) void k_zeroS(int* __restrict__ gcnt, int cap) {
  for (int i = threadIdx.x; i < cap; i += BLK) gcnt[i] = 0;
}

// ---------------- coarse histogram: NS slices, LDS-private ----------------
__global__ __launch_bounds__(BLK) void k_hist49(const int* __restrict__ dst,
                                                int* __restrict__ gcnt,
                                                int n, int E, int NS) {
  __shared__ int c[256];
  int tid = threadIdx.x;
  c[tid] = 0;
  __syncthreads();
  int base = blockIdx.x * CHUNK;
#pragma unroll
  for (int j = 0; j < EJ; j++) {
    int idx = base + j * BLK + tid;
    if (idx < E) {
      int d = dst[idx];
      if ((unsigned)d < (unsigned)n) atomicAdd(&c[d >> SLB], 1);
    }
  }
  __syncthreads();
  if (tid < NS && c[tid]) atomicAdd(&gcnt[tid], c[tid]);
}

// ---------------- scan coarse counts -> segment starts (out of place) -------
__global__ __launch_bounds__(BLK) void k_scanS(const int* __restrict__ gcnt,
                                               int* __restrict__ segStart, int NS) {
  __shared__ int sd[BLK];
  int tid = threadIdx.x;
  int t = (tid < NS) ? gcnt[tid] : 0;
  sd[tid] = t;
  __syncthreads();
  int run = t;
  for (int off = 1; off < BLK; off <<= 1) {
    int u = (tid >= off) ? sd[tid - off] : 0;
    __syncthreads();
    run += u;
    sd[tid] = run;
    __syncthreads();
  }
  if (tid < NS) segStart[tid] = run - t;  // exclusive
  if (tid == 0) segStart[NS] = sd[BLK - 1];  // grand total
}

__global__ __launch_bounds__(BLK) void k_copyS(const int* __restrict__ segStart,
                                               int* __restrict__ segCur, int NS) {
  int tid = threadIdx.x;
  if (tid < NS) segCur[tid] = segStart[tid];
}

// ---------------- bucket edges into coarse slice segments (packed int2) -----
// bpk[p] = { (dstLocal<<20) | src, ew }   (requires n <= 2^20)
__global__ __launch_bounds__(BLK) void k_bucket(const int* __restrict__ src,
                                                const int* __restrict__ dst,
                                                const float* __restrict__ ew,
                                                int* __restrict__ segCur,
                                                int2* __restrict__ bpk,
                                                int n, int E, int NS) {
  __shared__ int c[256], b[256], o[256];
  int tid = threadIdx.x;
  c[tid] = 0; o[tid] = 0;
  __syncthreads();
  int base = blockIdx.x * CHUNK;
  int dloc[EJ];
#pragma unroll
  for (int j = 0; j < EJ; j++) {
    int idx = base + j * BLK + tid;
    int d = -1;
    if (idx < E) {
      d = dst[idx];
      if ((unsigned)d >= (unsigned)n) d = -1;
    }
    dloc[j] = d;
    if (d >= 0) atomicAdd(&c[d >> SLB], 1);
  }
  __syncthreads();
  if (tid < NS && c[tid]) b[tid] = atomicAdd(&segCur[tid], c[tid]);
  __syncthreads();
#pragma unroll
  for (int j = 0; j < EJ; j++) {
    int idx = base + j * BLK + tid;
    int d = dloc[j];
    if (d >= 0) {
      int s = d >> SLB;
      int p = b[s] + atomicAdd(&o[s], 1);
      p = min(max(p, 0), E - 1);  // clamp safety
      int packed = ((d & (SLN - 1)) << 20) | (src[idx] & 0xFFFFF);
      bpk[p] = make_int2(packed, __float_as_int(ew[idx]));
    }
  }
}

// ---------------- per-slice counting sort (all LDS) + rs + es + dinv --------
__global__ __launch_bounds__(BLK) void k_slice(const int2* __restrict__ bpk,
                                               const int* __restrict__ segStart,
                                               int2* __restrict__ es,
                                               int* __restrict__ rs,
                                               float* __restrict__ dinv,
                                               int n, int E, int NS) {
  __shared__ int h[SLN];
  __shared__ int cu[SLN];
  __shared__ float wsum[SLN];
  __shared__ int sd[BLK];
  int s = blockIdx.x, tid = threadIdx.x;
  int node0 = s << SLB;
  int node1 = min(node0 + SLN, n);
  int sn = node1 - node0;
  int e0 = segStart[s], e1 = segStart[s + 1];
  e0 = max(0, min(e0, E));
  e1 = max(e0, min(e1, E));
  for (int i = tid; i < SLN; i += BLK) { h[i] = 0; wsum[i] = 0.f; }
  __syncthreads();
  for (int e = e0 + tid; e < e1; e += BLK)
    atomicAdd(&h[((unsigned)bpk[e].x >> 20) & (SLN - 1)], 1);
  __syncthreads();
  // exclusive scan of h -> cu, 2 bins/thread
  int bbase = tid * 2;
  int l0 = h[bbase], l1 = h[bbase + 1];
  int t = l0 + l1;
  sd[tid] = t;
  __syncthreads();
  int run = t;
  for (int off = 1; off < BLK; off <<= 1) {
    int u = (tid >= off) ? sd[tid - off] : 0;
    __syncthreads();
    run += u;
    sd[tid] = run;
    __syncthreads();
  }
  int excl = run - t;
  cu[bbase] = excl;
  if (bbase < sn) rs[node0 + bbase] = e0 + excl;
  excl += l0;
  cu[bbase + 1] = excl;
  if (bbase + 1 < sn) rs[node0 + bbase + 1] = e0 + excl;
  if (s == NS - 1 && tid == 0) rs[n] = E;
  __syncthreads();
  // scatter into final CSR order + weighted-degree accumulation
  for (int e = e0 + tid; e < e1; e += BLK) {
    int2 pk = bpk[e];
    int dl = ((unsigned)pk.x >> 20) & (SLN - 1);
    int sv = pk.x & 0xFFFFF;
    float w = __int_as_float(pk.y);
    int p = e0 + atomicAdd(&cu[dl], 1);
    p = min(max(p, 0), E - 1);
    es[p] = make_int2(sv, pk.y);
    atomicAdd(&wsum[dl], w);
  }
  __syncthreads();
  for (int l = tid; l < sn; l += BLK) {
    float deg = 1.0f + wsum[l];
    dinv[node0 + l] = deg > 0.f ? rsqrtf(deg) : 0.f;
  }
}

// ---------------- GEMM1: h1s[n,64](bf16x2) = dinv * (x[n,128] @ W1[128,64]) --
__global__ __launch_bounds__(BLK) void k_gemm1(const float* __restrict__ x,
                                               const float* __restrict__ W,
                                               const float* __restrict__ dinv,
                                               unsigned* __restrict__ h1s, int n) {
  __shared__ float Ws[128 * 64];
  __shared__ float xs[16][128];
  int tid = threadIdx.x;
  const float4* W4 = (const float4*)W;
  float4* Ws4 = (float4*)Ws;
#pragma unroll
  for (int i = 0; i < 8; i++) Ws4[tid + i * BLK] = W4[tid + i * BLK];
  int row0 = blockIdx.x * 16;
  int nrows = min(16, n - row0);
  const float4* x4 = (const float4*)(x + (size_t)row0 * 128);
  float4* xs4 = (float4*)xs;
  for (int i = tid; i < nrows * 32; i += BLK) xs4[i] = x4[i];
  __syncthreads();
  int col = tid & 63, rg = tid >> 6;  // wave-uniform rg -> xs reads broadcast
  float acc0 = 0.f, acc1 = 0.f, acc2 = 0.f, acc3 = 0.f;
#pragma unroll 4
  for (int k = 0; k < 128; k++) {
    float w = Ws[k * 64 + col];
    acc0 += xs[rg][k] * w;
    acc1 += xs[rg + 4][k] * w;
    acc2 += xs[rg + 8][k] * w;
    acc3 += xs[rg + 12][k] * w;
  }
  // scale by dinv[row], pack bf16x2 (even col packs {col, col+1})
  int r = row0 + rg;
  int rc0 = min(r, n - 1), rc1 = min(r + 4, n - 1),
      rc2 = min(r + 8, n - 1), rc3 = min(r + 12, n - 1);
  float v0 = acc0 * dinv[rc0], v1 = acc1 * dinv[rc1],
        v2 = acc2 * dinv[rc2], v3 = acc3 * dinv[rc3];
  float p0 = __shfl_xor(v0, 1, 64), p1 = __shfl_xor(v1, 1, 64),
        p2 = __shfl_xor(v2, 1, 64), p3 = __shfl_xor(v3, 1, 64);
  if ((col & 1) == 0) {
    int dw = col >> 1;
    unsigned u0 = (unsigned)f2bf(v0) | ((unsigned)f2bf(p0) << 16);
    unsigned u1 = (unsigned)f2bf(v1) | ((unsigned)f2bf(p1) << 16);
    unsigned u2 = (unsigned)f2bf(v2) | ((unsigned)f2bf(p2) << 16);
    unsigned u3 = (unsigned)f2bf(v3) | ((unsigned)f2bf(p3) << 16);
    if (r < n)      h1s[(size_t)r * 32 + dw]        = u0;
    if (r + 4 < n)  h1s[(size_t)(r + 4) * 32 + dw]  = u1;
    if (r + 8 < n)  h1s[(size_t)(r + 8) * 32 + dw]  = u2;
    if (r + 12 < n) h1s[(size_t)(r + 12) * 32 + dw] = u3;
  }
}

// ---------------- fused layer-1 aggregate + bias + ReLU + GEMM2 -------------
// One wave/node, dword-per-lane: lanes 0-31 = even edges, 32-63 = odd edges.
// MASKED full-width gathers: no serial tail loop (Poisson-16 degrees mean
// ~half the edges otherwise go through a 1-outstanding-load tail).
__global__ __launch_bounds__(BLK) void k_agg1f(const float* __restrict__ dinv,
                                               const int* __restrict__ rs,
                                               const int2* __restrict__ es,
                                               const unsigned* __restrict__ h1s,
                                               const float* __restrict__ b1,
                                               const float* __restrict__ W2,
                                               unsigned* __restrict__ h2s, int n, int E) {
  __shared__ float W2s[64 * 16];
  int tid = threadIdx.x;
  for (int i = tid; i < 1024; i += BLK) W2s[i] = W2[i];
  int v = blockIdx.x * 4 + (tid >> 6);
  int lane = tid & 63;
  int half = lane >> 5;   // which edge of the pair
  int d = lane & 31;      // dword -> features 2d, 2d+1
  unsigned nm1 = (unsigned)(n - 1);
  int Em1 = E - 1;
  float ax = 0.f, ay = 0.f, di = 0.f;
  if (v < n) {
    int start = rs[v], end = rs[v + 1];
    start = max(0, min(start, E));
    end = max(start, min(end, E));
    di = dinv[v];
    if (half == 0) {
      unsigned us = h1s[(size_t)v * 32 + d];  // self (h1s already has dinv[v])
      ax = bflo(us); ay = bfhi(us);
    }
    for (int i = start; i < end; i += 16) {
      int2 ee[8];
      float w[8];
      unsigned g[8];
#pragma unroll
      for (int j = 0; j < 8; j++) {
        int idx = i + 2 * j + half;
        ee[j] = es[min(idx, Em1)];
        w[j] = (idx < end) ? __int_as_float(ee[j].y) : 0.f;
      }
#pragma unroll
      for (int j = 0; j < 8; j++)
        g[j] = h1s[(size_t)min((unsigned)ee[j].x, nm1) * 32 + d];
#pragma unroll
      for (int j = 0; j < 8; j++) {
        ax += w[j] * bflo(g[j]);
        ay += w[j] * bfhi(g[j]);
      }
    }
  }
  // fold halves, redistribute to feature-per-lane layout
  ax += __shfl_xor(ax, 32, 64);
  ay += __shfl_xor(ay, 32, 64);
  float rx = __shfl(ax, lane >> 1, 64);
  float ry = __shfl(ay, lane >> 1, 64);
  float av = (lane & 1) ? ry : rx;
  float r = fmaxf(di * av + b1[lane], 0.f);
  __syncthreads();  // W2s ready (all threads reach: no early returns above)
  int q = lane >> 4, c = lane & 15;
  float p = 0.f;
#pragma unroll
  for (int j = 0; j < 16; j++) {
    float rv = __shfl(r, 16 * q + j, 64);
    p += rv * W2s[(16 * q + j) * 16 + c];
  }
  p += __shfl_xor(p, 16, 64);
  p += __shfl_xor(p, 32, 64);
  p *= di;  // store h2s = dinv[v] * h2[v]
  float pp = __shfl_xor(p, 1, 64);
  if (v < n && lane < 16 && (lane & 1) == 0)
    h2s[(size_t)v * 8 + (lane >> 1)] = (unsigned)f2bf(p) | ((unsigned)f2bf(pp) << 16);
}

// ---------------- fused layer-2 aggregate + bias + log_softmax --------------
// 16-lane group per node; two 8-lane subgroups; masked full-width gathers.
__global__ __launch_bounds__(BLK) void k_agg2f(const float* __restrict__ dinv,
                                               const int* __restrict__ rs,
                                               const int2* __restrict__ es,
                                               const unsigned* __restrict__ h2s,
                                               const float* __restrict__ b2,
                                               float* __restrict__ out, int n, int E) {
  int tid = threadIdx.x;
  int v = blockIdx.x * 16 + (tid >> 4);
  int j = tid & 15;
  if (v >= n) return;
  int g8 = j >> 3, d = j & 7;  // subgroup / dword (features 2d, 2d+1)
  unsigned nm1 = (unsigned)(n - 1);
  int Em1 = E - 1;
  int start = rs[v], end = rs[v + 1];
  start = max(0, min(start, E));
  end = max(start, min(end, E));
  float di = dinv[v];
  float ax = 0.f, ay = 0.f;
  if (g8 == 0) {
    unsigned us = h2s[(size_t)v * 8 + d];
    ax = bflo(us); ay = bfhi(us);
  }
  for (int i = start; i < end; i += 8) {
    int2 ee[4];
    float w[4];
    unsigned g[4];
#pragma unroll
    for (int k = 0; k < 4; k++) {
      int idx = i + 2 * k + g8;
      ee[k] = es[min(idx, Em1)];
      w[k] = (idx < end) ? __int_as_float(ee[k].y) : 0.f;
    }
#pragma unroll
    for (int k = 0; k < 4; k++)
      g[k] = h2s[(size_t)min((unsigned)ee[k].x, nm1) * 8 + d];
#pragma unroll
    for (int k = 0; k < 4; k++) {
      ax += w[k] * bflo(g[k]);
      ay += w[k] * bfhi(g[k]);
    }
  }
  // fold subgroups, redistribute to feature-per-lane within the 16-lane group
  ax += __shfl_xor(ax, 8, 64);
  ay += __shfl_xor(ay, 8, 64);
  int lane = tid & 63;
  int base = lane & ~15;
  float rx = __shfl(ax, base + (j >> 1), 64);
  float ry = __shfl(ay, base + (j >> 1), 64);
  float av = (j & 1) ? ry : rx;
  float acc = di * av + b2[j];
  float m = acc;
  m = fmaxf(m, __shfl_xor(m, 1, 64));
  m = fmaxf(m, __shfl_xor(m, 2, 64));
  m = fmaxf(m, __shfl_xor(m, 4, 64));
  m = fmaxf(m, __shfl_xor(m, 8, 64));
  float ex = expf(acc - m);
  float s = ex;
  s += __shfl_xor(s, 1, 64);
  s += __shfl_xor(s, 2, 64);
  s += __shfl_xor(s, 4, 64);
  s += __shfl_xor(s, 8, 64);
  out[(size_t)v * 16 + j] = acc - m - logf(s);
}

extern "C" void kernel_launch(void* const* d_in, const int* in_sizes, int n_in,
                              void* d_out, int out_size, void* d_ws, size_t ws_size,
                              hipStream_t stream) {
  const float* x  = (const float*)d_in[0];
  const int*   ei = (const int*)d_in[1];   // int32 [2,E]
  const float* ew = (const float*)d_in[2];
  const float* W1 = (const float*)d_in[3];
  const float* b1 = (const float*)d_in[4];
  const float* W2 = (const float*)d_in[5];
  const float* b2 = (const float*)d_in[6];
  float* out = (float*)d_out;

  int n = in_sizes[0] / 128;
  int E = in_sizes[2];
  const int* src = ei;
  const int* dst = ei + E;

  int NS = ((n - 1) >> SLB) + 1;  // 196 for n=100k
  if (NS > 256) NS = 256;         // safety (n=100k fine)
  const int NSCAP = 260;

  // workspace: all arrays at 16B-aligned offsets (R5 lesson: int2 alignment!)
  char* wp = (char*)d_ws;
  auto alloc = [&](size_t bytes) -> char* {
    char* r = wp;
    wp += (bytes + 15) & ~(size_t)15;
    return r;
  };
  int*      gcnt     = (int*)alloc((size_t)NSCAP * 4);
  int*      segStart = (int*)alloc((size_t)(NSCAP + 1) * 4);
  int*      segCur   = (int*)alloc((size_t)NSCAP * 4);
  int2*     bpk      = (int2*)alloc((size_t)E * 8);
  int2*     es       = (int2*)alloc((size_t)E * 8);
  int*      rs       = (int*)alloc((size_t)(n + 1) * 4);
  float*    dinv     = (float*)alloc((size_t)n * 4);
  unsigned* h1s      = (unsigned*)alloc((size_t)n * 32 * 4);
  unsigned* h2s      = (unsigned*)alloc((size_t)n * 8 * 4);

  int gC = (E + CHUNK - 1) / CHUNK;  // 391 for E=1.6M

  k_zeroS<<<1, BLK, 0, stream>>>(gcnt, NSCAP);
  k_hist49<<<gC, BLK, 0, stream>>>(dst, gcnt, n, E, NS);
  k_scanS<<<1, BLK, 0, stream>>>(gcnt, segStart, NS);
  k_copyS<<<1, BLK, 0, stream>>>(segStart, segCur, NS);
  k_bucket<<<gC, BLK, 0, stream>>>(src, dst, ew, segCur, bpk, n, E, NS);
  k_slice<<<NS, BLK, 0, stream>>>(bpk, segStart, es, rs, dinv, n, E, NS);

  k_gemm1<<<(n + 15) / 16, BLK, 0, stream>>>(x, W1, dinv, h1s, n);
  k_agg1f<<<(n + 3) / 4, BLK, 0, stream>>>(dinv, rs, es, h1s, b1, W2, h2s, n, E);
  k_agg2f<<<(n + 15) / 16, BLK, 0, stream>>>(dinv, rs, es, h2s, b2, out, n, E);
}

// Round 11
// 292.309 us; speedup vs baseline: 2.4175x; 1.0139x over previous
//
#include <hip/hip_runtime.h>
#include <cstdint>

#define BLK 256
#define EJ 16
#define CHUNK (BLK * EJ)   // 4096 edges per bucket block
#define SLB 8              // slice = 256 nodes
#define SLN 256
#define SCAP 6144          // slice capacity (mean 4092 @ E=1.6M/NS=391; +32 sigma)

__device__ inline unsigned short f2bf(float f) {  // RNE
  unsigned u = __float_as_uint(f);
  return (unsigned short)((u + 0x7FFF + ((u >> 16) & 1)) >> 16);
}
__device__ inline float bflo(unsigned u) { return __uint_as_float(u << 16); }
__device__ inline float bfhi(unsigned u) { return __uint_as_float(u & 0xFFFF0000u); }

// ---------------- init per-slice cursors to slice base ----------------
__global__ __launch_bounds__(BLK) void k_zeroC(int* __restrict__ cur, int NS) {
  int s = blockIdx.x * BLK + threadIdx.x;
  if (s < NS) cur[s] = s * SCAP;
}

// ---------------- bucket edges into fixed-capacity slice bins ----------------
// bpk[p] = { (dstLocal<<20) | src, ew }   (requires n <= 2^20, dstLocal < 256)
__global__ __launch_bounds__(BLK) void k_bucket(const int* __restrict__ src,
                                                const int* __restrict__ dst,
                                                const float* __restrict__ ew,
                                                int* __restrict__ cur,
                                                int2* __restrict__ bpk,
                                                int n, int E, int NS) {
  __shared__ int c[512], b[512], o[512];
  int tid = threadIdx.x;
  c[tid] = 0; o[tid] = 0; c[tid + 256] = 0; o[tid + 256] = 0;
  __syncthreads();
  int base = blockIdx.x * CHUNK;
  int dloc[EJ];
#pragma unroll
  for (int j = 0; j < EJ; j++) {
    int idx = base + j * BLK + tid;
    int d = -1;
    if (idx < E) {
      d = dst[idx];
      if ((unsigned)d >= (unsigned)n) d = -1;
    }
    dloc[j] = d;
    if (d >= 0) atomicAdd(&c[d >> SLB], 1);
  }
  __syncthreads();
  for (int s = tid; s < NS; s += BLK)
    if (c[s]) b[s] = atomicAdd(&cur[s], c[s]);
  __syncthreads();
#pragma unroll
  for (int j = 0; j < EJ; j++) {
    int idx = base + j * BLK + tid;
    int d = dloc[j];
    if (d >= 0) {
      int s = d >> SLB;
      int p = b[s] + atomicAdd(&o[s], 1);
      p = min(max(p, s * SCAP), (s + 1) * SCAP - 1);  // clamp into slice
      int packed = ((d & (SLN - 1)) << 20) | (src[idx] & 0xFFFFF);
      bpk[p] = make_int2(packed, __float_as_int(ew[idx]));
    }
  }
}

// ---------------- per-slice counting sort (all LDS) + rs/rse + dinv ---------
__global__ __launch_bounds__(BLK) void k_slice(const int2* __restrict__ bpk,
                                               const int* __restrict__ cur,
                                               int2* __restrict__ es,
                                               int* __restrict__ rs,
                                               int* __restrict__ rse,
                                               float* __restrict__ dinv,
                                               int n, int E, int NS) {
  __shared__ int h[SLN];
  __shared__ int cu[SLN];
  __shared__ float wsum[SLN];
  __shared__ int sd[BLK];
  int s = blockIdx.x, tid = threadIdx.x;
  int node0 = s << SLB;
  int sn = min(SLN, n - node0);
  int e0 = s * SCAP;
  int e1 = cur[s];
  e1 = max(e0, min(e1, e0 + SCAP));
  h[tid] = 0; wsum[tid] = 0.f;
  __syncthreads();
  for (int e = e0 + tid; e < e1; e += BLK)
    atomicAdd(&h[((unsigned)bpk[e].x >> 20) & (SLN - 1)], 1);
  __syncthreads();
  // exclusive scan, 1 bin/thread
  int loc = h[tid];
  sd[tid] = loc;
  __syncthreads();
  int run = loc;
  for (int off = 1; off < BLK; off <<= 1) {
    int u = (tid >= off) ? sd[tid - off] : 0;
    __syncthreads();
    run += u;
    sd[tid] = run;
    __syncthreads();
  }
  int excl = run - loc;
  cu[tid] = excl;
  if (tid < sn) {
    rs[node0 + tid] = e0 + excl;
    rse[node0 + tid] = e0 + excl + loc;
  }
  __syncthreads();
  // scatter into final CSR order + weighted-degree accumulation
  for (int e = e0 + tid; e < e1; e += BLK) {
    int2 pk = bpk[e];
    int dl = ((unsigned)pk.x >> 20) & (SLN - 1);
    int sv = pk.x & 0xFFFFF;
    float w = __int_as_float(pk.y);
    int p = e0 + atomicAdd(&cu[dl], 1);
    p = min(max(p, e0), e0 + SCAP - 1);
    es[p] = make_int2(sv, pk.y);
    atomicAdd(&wsum[dl], w);
  }
  __syncthreads();
  if (tid < sn) {
    float deg = 1.0f + wsum[tid];
    dinv[node0 + tid] = deg > 0.f ? rsqrtf(deg) : 0.f;
  }
}

// ---------------- GEMM1: h1s[n,64](bf16x2) = dinv * (x[n,128] @ W1[128,64]) --
__global__ __launch_bounds__(BLK) void k_gemm1(const float* __restrict__ x,
                                               const float* __restrict__ W,
                                               const float* __restrict__ dinv,
                                               unsigned* __restrict__ h1s, int n) {
  __shared__ float Ws[128 * 64];
  __shared__ float xs[16][128];
  int tid = threadIdx.x;
  const float4* W4 = (const float4*)W;
  float4* Ws4 = (float4*)Ws;
#pragma unroll
  for (int i = 0; i < 8; i++) Ws4[tid + i * BLK] = W4[tid + i * BLK];
  int row0 = blockIdx.x * 16;
  int nrows = min(16, n - row0);
  const float4* x4 = (const float4*)(x + (size_t)row0 * 128);
  float4* xs4 = (float4*)xs;
  for (int i = tid; i < nrows * 32; i += BLK) xs4[i] = x4[i];
  __syncthreads();
  int col = tid & 63, rg = tid >> 6;  // wave-uniform rg -> xs reads broadcast
  float acc0 = 0.f, acc1 = 0.f, acc2 = 0.f, acc3 = 0.f;
#pragma unroll 4
  for (int k = 0; k < 128; k++) {
    float w = Ws[k * 64 + col];
    acc0 += xs[rg][k] * w;
    acc1 += xs[rg + 4][k] * w;
    acc2 += xs[rg + 8][k] * w;
    acc3 += xs[rg + 12][k] * w;
  }
  // scale by dinv[row], pack bf16x2 (even col packs {col, col+1})
  int r = row0 + rg;
  int rc0 = min(r, n - 1), rc1 = min(r + 4, n - 1),
      rc2 = min(r + 8, n - 1), rc3 = min(r + 12, n - 1);
  float v0 = acc0 * dinv[rc0], v1 = acc1 * dinv[rc1],
        v2 = acc2 * dinv[rc2], v3 = acc3 * dinv[rc3];
  float p0 = __shfl_xor(v0, 1, 64), p1 = __shfl_xor(v1, 1, 64),
        p2 = __shfl_xor(v2, 1, 64), p3 = __shfl_xor(v3, 1, 64);
  if ((col & 1) == 0) {
    int dw = col >> 1;
    unsigned u0 = (unsigned)f2bf(v0) | ((unsigned)f2bf(p0) << 16);
    unsigned u1 = (unsigned)f2bf(v1) | ((unsigned)f2bf(p1) << 16);
    unsigned u2 = (unsigned)f2bf(v2) | ((unsigned)f2bf(p2) << 16);
    unsigned u3 = (unsigned)f2bf(v3) | ((unsigned)f2bf(p3) << 16);
    if (r < n)      h1s[(size_t)r * 32 + dw]        = u0;
    if (r + 4 < n)  h1s[(size_t)(r + 4) * 32 + dw]  = u1;
    if (r + 8 < n)  h1s[(size_t)(r + 8) * 32 + dw]  = u2;
    if (r + 12 < n) h1s[(size_t)(r + 12) * 32 + dw] = u3;
  }
}

// ---------------- fused layer-1 aggregate + bias + ReLU + GEMM2 -------------
// One wave/node. uint4 gathers: 8 lanes per edge (oct = lane>>3 picks the
// edge, q8 = lane&7 picks 16B = 8 features). One gather inst = 8 edges.
// Masked idx clamps to end-1 (row's own region — es is slice-padded!).
__global__ __launch_bounds__(BLK) void k_agg1f(const float* __restrict__ dinv,
                                               const int* __restrict__ rs,
                                               const int* __restrict__ rse,
                                               const int2* __restrict__ es,
                                               const unsigned* __restrict__ h1s,
                                               const float* __restrict__ b1,
                                               const float* __restrict__ W2,
                                               unsigned* __restrict__ h2s, int n, int E) {
  __shared__ float W2s[64 * 16];
  int tid = threadIdx.x;
  for (int i = tid; i < 1024; i += BLK) W2s[i] = W2[i];
  int v = blockIdx.x * 4 + (tid >> 6);
  int lane = tid & 63;
  int oct = lane >> 3;   // edge slot 0..7
  int q8 = lane & 7;     // owns dwords 4*q8..4*q8+3 = features 8*q8..8*q8+7
  unsigned nm1 = (unsigned)(n - 1);
  float a0 = 0.f, a1 = 0.f, a2 = 0.f, a3 = 0.f;
  float a4 = 0.f, a5 = 0.f, a6 = 0.f, a7 = 0.f;
  float di = 0.f;
  if (v < n) {
    int start = rs[v], end = rse[v];
    di = dinv[v];
    if (oct == 0) {  // self term (h1s already carries dinv[v])
      const uint4* hp = (const uint4*)(h1s + (size_t)v * 32);
      uint4 g = hp[q8];
      a0 += bflo(g.x); a1 += bfhi(g.x);
      a2 += bflo(g.y); a3 += bfhi(g.y);
      a4 += bflo(g.z); a5 += bfhi(g.z);
      a6 += bflo(g.w); a7 += bfhi(g.w);
    }
    for (int i = start; i < end; i += 16) {
#pragma unroll
      for (int j = 0; j < 2; j++) {
        int idx = i + 8 * j + oct;
        int2 e = es[min(idx, end - 1)];   // in-row clamp (loop ran => end>start)
        float w = (idx < end) ? __int_as_float(e.y) : 0.f;
        const uint4* hp = (const uint4*)(h1s + (size_t)min((unsigned)e.x, nm1) * 32);
        uint4 g = hp[q8];
        a0 += w * bflo(g.x); a1 += w * bfhi(g.x);
        a2 += w * bflo(g.y); a3 += w * bfhi(g.y);
        a4 += w * bflo(g.z); a5 += w * bfhi(g.z);
        a6 += w * bflo(g.w); a7 += w * bfhi(g.w);
      }
    }
  }
  // fold octets: every lane then holds full sums for its q8 feature group
  a0 += __shfl_xor(a0, 8, 64);  a0 += __shfl_xor(a0, 16, 64);  a0 += __shfl_xor(a0, 32, 64);
  a1 += __shfl_xor(a1, 8, 64);  a1 += __shfl_xor(a1, 16, 64);  a1 += __shfl_xor(a1, 32, 64);
  a2 += __shfl_xor(a2, 8, 64);  a2 += __shfl_xor(a2, 16, 64);  a2 += __shfl_xor(a2, 32, 64);
  a3 += __shfl_xor(a3, 8, 64);  a3 += __shfl_xor(a3, 16, 64);  a3 += __shfl_xor(a3, 32, 64);
  a4 += __shfl_xor(a4, 8, 64);  a4 += __shfl_xor(a4, 16, 64);  a4 += __shfl_xor(a4, 32, 64);
  a5 += __shfl_xor(a5, 8, 64);  a5 += __shfl_xor(a5, 16, 64);  a5 += __shfl_xor(a5, 32, 64);
  a6 += __shfl_xor(a6, 8, 64);  a6 += __shfl_xor(a6, 16, 64);  a6 += __shfl_xor(a6, 32, 64);
  a7 += __shfl_xor(a7, 8, 64);  a7 += __shfl_xor(a7, 16, 64);  a7 += __shfl_xor(a7, 32, 64);
  // redistribute: lane l wants feature l = 8*(l>>3) + (l&7)
  int srcl = lane >> 3;
  float r0 = __shfl(a0, srcl, 64), r1 = __shfl(a1, srcl, 64);
  float r2 = __shfl(a2, srcl, 64), r3 = __shfl(a3, srcl, 64);
  float r4 = __shfl(a4, srcl, 64), r5 = __shfl(a5, srcl, 64);
  float r6 = __shfl(a6, srcl, 64), r7 = __shfl(a7, srcl, 64);
  int cc = lane & 7;
  float t0 = (cc & 1) ? r1 : r0;
  float t1 = (cc & 1) ? r3 : r2;
  float t2 = (cc & 1) ? r5 : r4;
  float t3 = (cc & 1) ? r7 : r6;
  float u0 = (cc & 2) ? t1 : t0;
  float u1 = (cc & 2) ? t3 : t2;
  float av = (cc & 4) ? u1 : u0;
  float r = fmaxf(di * av + b1[lane], 0.f);
  __syncthreads();  // W2s ready (all threads reach: no early returns above)
  int q = lane >> 4, c = lane & 15;
  float p = 0.f;
#pragma unroll
  for (int j = 0; j < 16; j++) {
    float rv = __shfl(r, 16 * q + j, 64);
    p += rv * W2s[(16 * q + j) * 16 + c];
  }
  p += __shfl_xor(p, 16, 64);
  p += __shfl_xor(p, 32, 64);
  p *= di;  // store h2s = dinv[v] * h2[v]
  float pp = __shfl_xor(p, 1, 64);
  if (v < n && lane < 16 && (lane & 1) == 0)
    h2s[(size_t)v * 8 + (lane >> 1)] = (unsigned)f2bf(p) | ((unsigned)f2bf(pp) << 16);
}

// ---------------- fused layer-2 aggregate + bias + log_softmax --------------
// 16-lane group per node; two 8-lane subgroups; masked in-row-clamped gathers.
__global__ __launch_bounds__(BLK) void k_agg2f(const float* __restrict__ dinv,
                                               const int* __restrict__ rs,
                                               const int* __restrict__ rse,
                                               const int2* __restrict__ es,
                                               const unsigned* __restrict__ h2s,
                                               const float* __restrict__ b2,
                                               float* __restrict__ out, int n, int E) {
  int tid = threadIdx.x;
  int v = blockIdx.x * 16 + (tid >> 4);
  int j = tid & 15;
  if (v >= n) return;
  int g8 = j >> 3, d = j & 7;  // subgroup / dword (features 2d, 2d+1)
  unsigned nm1 = (unsigned)(n - 1);
  int start = rs[v], end = rse[v];
  float di = dinv[v];
  float ax = 0.f, ay = 0.f;
  if (g8 == 0) {
    unsigned us = h2s[(size_t)v * 8 + d];
    ax = bflo(us); ay = bfhi(us);
  }
  for (int i = start; i < end; i += 8) {
    int2 ee[4];
    float w[4];
    unsigned g[4];
#pragma unroll
    for (int k = 0; k < 4; k++) {
      int idx = i + 2 * k + g8;
      ee[k] = es[min(idx, end - 1)];   // in-row clamp
      w[k] = (idx < end) ? __int_as_float(ee[k].y) : 0.f;
    }
#pragma unroll
    for (int k = 0; k < 4; k++)
      g[k] = h2s[(size_t)min((unsigned)ee[k].x, nm1) * 8 + d];
#pragma unroll
    for (int k = 0; k < 4; k++) {
      ax += w[k] * bflo(g[k]);
      ay += w[k] * bfhi(g[k]);
    }
  }
  // fold subgroups, redistribute to feature-per-lane within the 16-lane group
  ax += __shfl_xor(ax, 8, 64);
  ay += __shfl_xor(ay, 8, 64);
  int lane = tid & 63;
  int base = lane & ~15;
  float rx = __shfl(ax, base + (j >> 1), 64);
  float ry = __shfl(ay, base + (j >> 1), 64);
  float av = (j & 1) ? ry : rx;
  float acc = di * av + b2[j];
  float m = acc;
  m = fmaxf(m, __shfl_xor(m, 1, 64));
  m = fmaxf(m, __shfl_xor(m, 2, 64));
  m = fmaxf(m, __shfl_xor(m, 4, 64));
  m = fmaxf(m, __shfl_xor(m, 8, 64));
  float ex = expf(acc - m);
  float s = ex;
  s += __shfl_xor(s, 1, 64);
  s += __shfl_xor(s, 2, 64);
  s += __shfl_xor(s, 4, 64);
  s += __shfl_xor(s, 8, 64);
  out[(size_t)v * 16 + j] = acc - m - logf(s);
}

extern "C" void kernel_launch(void* const* d_in, const int* in_sizes, int n_in,
                              void* d_out, int out_size, void* d_ws, size_t ws_size,
                              hipStream_t stream) {
  const float* x  = (const float*)d_in[0];
  const int*   ei = (const int*)d_in[1];   // int32 [2,E]
  const float* ew = (const float*)d_in[2];
  const float* W1 = (const float*)d_in[3];
  const float* b1 = (const float*)d_in[4];
  const float* W2 = (const float*)d_in[5];
  const float* b2 = (const float*)d_in[6];
  float* out = (float*)d_out;

  int n = in_sizes[0] / 128;
  int E = in_sizes[2];
  const int* src = ei;
  const int* dst = ei + E;

  int NS = ((n - 1) >> SLB) + 1;  // 391 for n=100k
  size_t padE = (size_t)NS * SCAP;

  // workspace: all arrays at 16B-aligned offsets (R5 lesson: int2 alignment!)
  char* wp = (char*)d_ws;
  auto alloc = [&](size_t bytes) -> char* {
    char* r = wp;
    wp += (bytes + 15) & ~(size_t)15;
    return r;
  };
  int*      cur  = (int*)alloc((size_t)(NS + 4) * 4);
  int2*     bpk  = (int2*)alloc(padE * 8);
  int2*     es   = (int2*)alloc(padE * 8);
  int*      rs   = (int*)alloc((size_t)n * 4);
  int*      rse  = (int*)alloc((size_t)n * 4);
  float*    dinv = (float*)alloc((size_t)n * 4);
  unsigned* h1s  = (unsigned*)alloc((size_t)n * 32 * 4);
  unsigned* h2s  = (unsigned*)alloc((size_t)n * 8 * 4);

  int gC = (E + CHUNK - 1) / CHUNK;  // 391 for E=1.6M

  k_zeroC<<<(NS + BLK - 1) / BLK, BLK, 0, stream>>>(cur, NS);
  k_bucket<<<gC, BLK, 0, stream>>>(src, dst, ew, cur, bpk, n, E, NS);
  k_slice<<<NS, BLK, 0, stream>>>(bpk, cur, es, rs, rse, dinv, n, E, NS);

  k_gemm1<<<(n + 15) / 16, BLK, 0, stream>>>(x, W1, dinv, h1s, n);
  k_agg1f<<<(n + 3) / 4, BLK, 0, stream>>>(dinv, rs, rse, es, h1s, b1, W2, h2s, n, E);
  k_agg2f<<<(n + 15) / 16, BLK, 0, stream>>>(dinv, rs, rse, es, h2s, b2, out, n, E);
}

// Round 12
// 270.883 us; speedup vs baseline: 2.6087x; 1.0791x over previous
//
#include <hip/hip_runtime.h>
#include <cstdint>

#define BLK 256
#define EJ 16
#define CHUNK (BLK * EJ)   // 4096 edges per bucket block
#define SLB 8              // slice = 256 nodes
#define SLN 256
#define SCAP 6144          // slice capacity (mean 4092 @ E=1.6M/NS=391; +32 sigma)

__device__ inline unsigned short f2bf(float f) {  // RNE
  unsigned u = __float_as_uint(f);
  return (unsigned short)((u + 0x7FFF + ((u >> 16) & 1)) >> 16);
}
__device__ inline float bflo(unsigned u) { return __uint_as_float(u << 16); }
__device__ inline float bfhi(unsigned u) { return __uint_as_float(u & 0xFFFF0000u); }

// ---------------- init per-slice cursors to slice base ----------------
__global__ __launch_bounds__(BLK) void k_zeroC(int* __restrict__ cur, int NS) {
  int s = blockIdx.x * BLK + threadIdx.x;
  if (s < NS) cur[s] = s * SCAP;
}

// ---------------- bucket edges into fixed-capacity slice bins ----------------
// bpk[p] = { (dstLocal<<20) | src, ew }   (requires n <= 2^20, dstLocal < 256)
__global__ __launch_bounds__(BLK) void k_bucket(const int* __restrict__ src,
                                                const int* __restrict__ dst,
                                                const float* __restrict__ ew,
                                                int* __restrict__ cur,
                                                int2* __restrict__ bpk,
                                                int n, int E, int NS) {
  __shared__ int c[512], b[512], o[512];
  int tid = threadIdx.x;
  c[tid] = 0; o[tid] = 0; c[tid + 256] = 0; o[tid + 256] = 0;
  __syncthreads();
  int base = blockIdx.x * CHUNK;
  int dloc[EJ];
#pragma unroll
  for (int j = 0; j < EJ; j++) {
    int idx = base + j * BLK + tid;
    int d = -1;
    if (idx < E) {
      d = dst[idx];
      if ((unsigned)d >= (unsigned)n) d = -1;
    }
    dloc[j] = d;
    if (d >= 0) atomicAdd(&c[d >> SLB], 1);
  }
  __syncthreads();
  for (int s = tid; s < NS; s += BLK)
    if (c[s]) b[s] = atomicAdd(&cur[s], c[s]);
  __syncthreads();
#pragma unroll
  for (int j = 0; j < EJ; j++) {
    int idx = base + j * BLK + tid;
    int d = dloc[j];
    if (d >= 0) {
      int s = d >> SLB;
      int p = b[s] + atomicAdd(&o[s], 1);
      p = min(max(p, s * SCAP), (s + 1) * SCAP - 1);  // clamp into slice
      int packed = ((d & (SLN - 1)) << 20) | (src[idx] & 0xFFFFF);
      bpk[p] = make_int2(packed, __float_as_int(ew[idx]));
    }
  }
}

// ---------------- per-slice counting sort (all LDS) + rs/rse + dinv ---------
__global__ __launch_bounds__(BLK) void k_slice(const int2* __restrict__ bpk,
                                               const int* __restrict__ cur,
                                               int2* __restrict__ es,
                                               int* __restrict__ rs,
                                               int* __restrict__ rse,
                                               float* __restrict__ dinv,
                                               int n, int E, int NS) {
  __shared__ int h[SLN];
  __shared__ int cu[SLN];
  __shared__ float wsum[SLN];
  __shared__ int sd[BLK];
  int s = blockIdx.x, tid = threadIdx.x;
  int node0 = s << SLB;
  int sn = min(SLN, n - node0);
  int e0 = s * SCAP;
  int e1 = cur[s];
  e1 = max(e0, min(e1, e0 + SCAP));
  h[tid] = 0; wsum[tid] = 0.f;
  __syncthreads();
  for (int e = e0 + tid; e < e1; e += BLK)
    atomicAdd(&h[((unsigned)bpk[e].x >> 20) & (SLN - 1)], 1);
  __syncthreads();
  // exclusive scan, 1 bin/thread
  int loc = h[tid];
  sd[tid] = loc;
  __syncthreads();
  int run = loc;
  for (int off = 1; off < BLK; off <<= 1) {
    int u = (tid >= off) ? sd[tid - off] : 0;
    __syncthreads();
    run += u;
    sd[tid] = run;
    __syncthreads();
  }
  int excl = run - loc;
  cu[tid] = excl;
  if (tid < sn) {
    rs[node0 + tid] = e0 + excl;
    rse[node0 + tid] = e0 + excl + loc;
  }
  __syncthreads();
  // scatter into final CSR order + weighted-degree accumulation
  for (int e = e0 + tid; e < e1; e += BLK) {
    int2 pk = bpk[e];
    int dl = ((unsigned)pk.x >> 20) & (SLN - 1);
    int sv = pk.x & 0xFFFFF;
    float w = __int_as_float(pk.y);
    int p = e0 + atomicAdd(&cu[dl], 1);
    p = min(max(p, e0), e0 + SCAP - 1);
    es[p] = make_int2(sv, pk.y);
    atomicAdd(&wsum[dl], w);
  }
  __syncthreads();
  if (tid < sn) {
    float deg = 1.0f + wsum[tid];
    dinv[node0 + tid] = deg > 0.f ? rsqrtf(deg) : 0.f;
  }
}

// ---------------- GEMM1: h1s[n,64](bf16x2) = dinv * (x[n,128] @ W1[128,64]) --
__global__ __launch_bounds__(BLK) void k_gemm1(const float* __restrict__ x,
                                               const float* __restrict__ W,
                                               const float* __restrict__ dinv,
                                               unsigned* __restrict__ h1s, int n) {
  __shared__ float Ws[128 * 64];
  __shared__ float xs[16][128];
  int tid = threadIdx.x;
  const float4* W4 = (const float4*)W;
  float4* Ws4 = (float4*)Ws;
#pragma unroll
  for (int i = 0; i < 8; i++) Ws4[tid + i * BLK] = W4[tid + i * BLK];
  int row0 = blockIdx.x * 16;
  int nrows = min(16, n - row0);
  const float4* x4 = (const float4*)(x + (size_t)row0 * 128);
  float4* xs4 = (float4*)xs;
  for (int i = tid; i < nrows * 32; i += BLK) xs4[i] = x4[i];
  __syncthreads();
  int col = tid & 63, rg = tid >> 6;  // wave-uniform rg -> xs reads broadcast
  float acc0 = 0.f, acc1 = 0.f, acc2 = 0.f, acc3 = 0.f;
#pragma unroll 4
  for (int k = 0; k < 128; k++) {
    float w = Ws[k * 64 + col];
    acc0 += xs[rg][k] * w;
    acc1 += xs[rg + 4][k] * w;
    acc2 += xs[rg + 8][k] * w;
    acc3 += xs[rg + 12][k] * w;
  }
  // scale by dinv[row], pack bf16x2 (even col packs {col, col+1})
  int r = row0 + rg;
  int rc0 = min(r, n - 1), rc1 = min(r + 4, n - 1),
      rc2 = min(r + 8, n - 1), rc3 = min(r + 12, n - 1);
  float v0 = acc0 * dinv[rc0], v1 = acc1 * dinv[rc1],
        v2 = acc2 * dinv[rc2], v3 = acc3 * dinv[rc3];
  float p0 = __shfl_xor(v0, 1, 64), p1 = __shfl_xor(v1, 1, 64),
        p2 = __shfl_xor(v2, 1, 64), p3 = __shfl_xor(v3, 1, 64);
  if ((col & 1) == 0) {
    int dw = col >> 1;
    unsigned u0 = (unsigned)f2bf(v0) | ((unsigned)f2bf(p0) << 16);
    unsigned u1 = (unsigned)f2bf(v1) | ((unsigned)f2bf(p1) << 16);
    unsigned u2 = (unsigned)f2bf(v2) | ((unsigned)f2bf(p2) << 16);
    unsigned u3 = (unsigned)f2bf(v3) | ((unsigned)f2bf(p3) << 16);
    if (r < n)      h1s[(size_t)r * 32 + dw]        = u0;
    if (r + 4 < n)  h1s[(size_t)(r + 4) * 32 + dw]  = u1;
    if (r + 8 < n)  h1s[(size_t)(r + 8) * 32 + dw]  = u2;
    if (r + 12 < n) h1s[(size_t)(r + 12) * 32 + dw] = u3;
  }
}

// ---------------- fused layer-1 aggregate + bias + ReLU + GEMM2 -------------
// One wave/node, dword-per-lane (R9 layout): lanes 0-31 = even edge, 32-63 =
// odd edge; lane owns features {2d, 2d+1}. 16 edges/iter, 8 gathers in flight.
// Masked idx clamps to end-1 (in-row — es is slice-padded).
__global__ __launch_bounds__(BLK) void k_agg1f(const float* __restrict__ dinv,
                                               const int* __restrict__ rs,
                                               const int* __restrict__ rse,
                                               const int2* __restrict__ es,
                                               const unsigned* __restrict__ h1s,
                                               const float* __restrict__ b1,
                                               const float* __restrict__ W2,
                                               unsigned* __restrict__ h2s, int n, int E) {
  __shared__ float W2s[64 * 16];
  int tid = threadIdx.x;
  for (int i = tid; i < 1024; i += BLK) W2s[i] = W2[i];
  int v = blockIdx.x * 4 + (tid >> 6);
  int lane = tid & 63;
  int half = lane >> 5;   // which edge of the pair
  int d = lane & 31;      // dword -> features 2d, 2d+1
  unsigned nm1 = (unsigned)(n - 1);
  float ax = 0.f, ay = 0.f, di = 0.f;
  if (v < n) {
    int start = rs[v], end = rse[v];
    di = dinv[v];
    if (half == 0) {
      unsigned us = h1s[(size_t)v * 32 + d];  // self (h1s already has dinv[v])
      ax = bflo(us); ay = bfhi(us);
    }
    for (int i = start; i < end; i += 16) {
      int2 ee[8];
      float w[8];
      unsigned g[8];
#pragma unroll
      for (int j = 0; j < 8; j++) {
        int idx = i + 2 * j + half;
        ee[j] = es[min(idx, end - 1)];   // in-row clamp (loop ran => end>start)
        w[j] = (idx < end) ? __int_as_float(ee[j].y) : 0.f;
      }
#pragma unroll
      for (int j = 0; j < 8; j++)
        g[j] = h1s[(size_t)min((unsigned)ee[j].x, nm1) * 32 + d];
#pragma unroll
      for (int j = 0; j < 8; j++) {
        ax += w[j] * bflo(g[j]);
        ay += w[j] * bfhi(g[j]);
      }
    }
  }
  // fold halves, redistribute to feature-per-lane layout
  ax += __shfl_xor(ax, 32, 64);
  ay += __shfl_xor(ay, 32, 64);
  float rx = __shfl(ax, lane >> 1, 64);
  float ry = __shfl(ay, lane >> 1, 64);
  float av = (lane & 1) ? ry : rx;
  float r = fmaxf(di * av + b1[lane], 0.f);
  __syncthreads();  // W2s ready (all threads reach: no early returns above)
  int q = lane >> 4, c = lane & 15;
  float p = 0.f;
#pragma unroll
  for (int j = 0; j < 16; j++) {
    float rv = __shfl(r, 16 * q + j, 64);
    p += rv * W2s[(16 * q + j) * 16 + c];
  }
  p += __shfl_xor(p, 16, 64);
  p += __shfl_xor(p, 32, 64);
  p *= di;  // store h2s = dinv[v] * h2[v]
  float pp = __shfl_xor(p, 1, 64);
  if (v < n && lane < 16 && (lane & 1) == 0)
    h2s[(size_t)v * 8 + (lane >> 1)] = (unsigned)f2bf(p) | ((unsigned)f2bf(pp) << 16);
}

// ---------------- fused layer-2 aggregate + bias + log_softmax --------------
// 16-lane group per node; two 8-lane subgroups; masked in-row-clamped gathers.
__global__ __launch_bounds__(BLK) void k_agg2f(const float* __restrict__ dinv,
                                               const int* __restrict__ rs,
                                               const int* __restrict__ rse,
                                               const int2* __restrict__ es,
                                               const unsigned* __restrict__ h2s,
                                               const float* __restrict__ b2,
                                               float* __restrict__ out, int n, int E) {
  int tid = threadIdx.x;
  int v = blockIdx.x * 16 + (tid >> 4);
  int j = tid & 15;
  if (v >= n) return;
  int g8 = j >> 3, d = j & 7;  // subgroup / dword (features 2d, 2d+1)
  unsigned nm1 = (unsigned)(n - 1);
  int start = rs[v], end = rse[v];
  float di = dinv[v];
  float ax = 0.f, ay = 0.f;
  if (g8 == 0) {
    unsigned us = h2s[(size_t)v * 8 + d];
    ax = bflo(us); ay = bfhi(us);
  }
  for (int i = start; i < end; i += 8) {
    int2 ee[4];
    float w[4];
    unsigned g[4];
#pragma unroll
    for (int k = 0; k < 4; k++) {
      int idx = i + 2 * k + g8;
      ee[k] = es[min(idx, end - 1)];   // in-row clamp
      w[k] = (idx < end) ? __int_as_float(ee[k].y) : 0.f;
    }
#pragma unroll
    for (int k = 0; k < 4; k++)
      g[k] = h2s[(size_t)min((unsigned)ee[k].x, nm1) * 8 + d];
#pragma unroll
    for (int k = 0; k < 4; k++) {
      ax += w[k] * bflo(g[k]);
      ay += w[k] * bfhi(g[k]);
    }
  }
  // fold subgroups, redistribute to feature-per-lane within the 16-lane group
  ax += __shfl_xor(ax, 8, 64);
  ay += __shfl_xor(ay, 8, 64);
  int lane = tid & 63;
  int base = lane & ~15;
  float rx = __shfl(ax, base + (j >> 1), 64);
  float ry = __shfl(ay, base + (j >> 1), 64);
  float av = (j & 1) ? ry : rx;
  float acc = di * av + b2[j];
  float m = acc;
  m = fmaxf(m, __shfl_xor(m, 1, 64));
  m = fmaxf(m, __shfl_xor(m, 2, 64));
  m = fmaxf(m, __shfl_xor(m, 4, 64));
  m = fmaxf(m, __shfl_xor(m, 8, 64));
  float ex = expf(acc - m);
  float s = ex;
  s += __shfl_xor(s, 1, 64);
  s += __shfl_xor(s, 2, 64);
  s += __shfl_xor(s, 4, 64);
  s += __shfl_xor(s, 8, 64);
  out[(size_t)v * 16 + j] = acc - m - logf(s);
}

extern "C" void kernel_launch(void* const* d_in, const int* in_sizes, int n_in,
                              void* d_out, int out_size, void* d_ws, size_t ws_size,
                              hipStream_t stream) {
  const float* x  = (const float*)d_in[0];
  const int*   ei = (const int*)d_in[1];   // int32 [2,E]
  const float* ew = (const float*)d_in[2];
  const float* W1 = (const float*)d_in[3];
  const float* b1 = (const float*)d_in[4];
  const float* W2 = (const float*)d_in[5];
  const float* b2 = (const float*)d_in[6];
  float* out = (float*)d_out;

  int n = in_sizes[0] / 128;
  int E = in_sizes[2];
  const int* src = ei;
  const int* dst = ei + E;

  int NS = ((n - 1) >> SLB) + 1;  // 391 for n=100k
  size_t padE = (size_t)NS * SCAP;

  // workspace: all arrays at 16B-aligned offsets (R5 lesson: int2 alignment!)
  char* wp = (char*)d_ws;
  auto alloc = [&](size_t bytes) -> char* {
    char* r = wp;
    wp += (bytes + 15) & ~(size_t)15;
    return r;
  };
  int*      cur  = (int*)alloc((size_t)(NS + 4) * 4);
  int2*     bpk  = (int2*)alloc(padE * 8);
  int2*     es   = (int2*)alloc(padE * 8);
  int*      rs   = (int*)alloc((size_t)n * 4);
  int*      rse  = (int*)alloc((size_t)n * 4);
  float*    dinv = (float*)alloc((size_t)n * 4);
  unsigned* h1s  = (unsigned*)alloc((size_t)n * 32 * 4);
  unsigned* h2s  = (unsigned*)alloc((size_t)n * 8 * 4);

  int gC = (E + CHUNK - 1) / CHUNK;  // 391 for E=1.6M

  k_zeroC<<<(NS + BLK - 1) / BLK, BLK, 0, stream>>>(cur, NS);
  k_bucket<<<gC, BLK, 0, stream>>>(src, dst, ew, cur, bpk, n, E, NS);
  k_slice<<<NS, BLK, 0, stream>>>(bpk, cur, es, rs, rse, dinv, n, E, NS);

  k_gemm1<<<(n + 15) / 16, BLK, 0, stream>>>(x, W1, dinv, h1s, n);
  k_agg1f<<<(n + 3) / 4, BLK, 0, stream>>>(dinv, rs, rse, es, h1s, b1, W2, h2s, n, E);
  k_agg2f<<<(n + 15) / 16, BLK, 0, stream>>>(dinv, rs, rse, es, h2s, b2, out, n, E);
}